// Round 7
// baseline (187.517 us; speedup 1.0000x reference)
//
#include <hip/hip_runtime.h>
#include <math.h>

#define L_SEQ 8192
#define H_DIM 1024
#define N_DIM 1024
#define K2    2048          // packed K = 2*H = 2*N
#define NCHUNK 64
#define CHUNK 128

typedef unsigned short u16;
typedef __attribute__((ext_vector_type(8))) __bf16 bf16x8;
typedef __attribute__((ext_vector_type(4))) float  f32x4;

__device__ __forceinline__ u16 f2bf(float x) {
    unsigned int u = __float_as_uint(x);
    u = (u + 0x7fffu + ((u >> 16) & 1u)) >> 16;   // RNE
    return (u16)u;
}
__device__ __forceinline__ float bf2f(u16 h) {
    return __uint_as_float(((unsigned int)h) << 16);
}

__device__ __forceinline__ void gload_lds16(const void* g, void* s) {
    __builtin_amdgcn_global_load_lds(
        (const __attribute__((address_space(1))) unsigned int*)g,
        (__attribute__((address_space(3))) unsigned int*)s, 16, 0, 0);
}

// ---------------------------------------------------------------------------
// Lambda = exp(-exp(nu_log) + i*exp(theta_log))
// ---------------------------------------------------------------------------
__global__ void lru_lambda(const float* __restrict__ nu_log,
                           const float* __restrict__ theta_log,
                           float* __restrict__ Lr, float* __restrict__ Li) {
    int n = blockIdx.x * 256 + threadIdx.x;
    float nu  = expf(nu_log[n]);
    float th  = expf(theta_log[n]);
    float mag = expf(-nu);
    Lr[n] = mag * cosf(th);
    Li[n] = mag * sinf(th);
}

// ---------------------------------------------------------------------------
// Pack u -> A' bf16 [L][2H]: cols [0,1024)=u_r, [1024,2048)=u_i
// ---------------------------------------------------------------------------
__global__ void pack_u(const float* __restrict__ R, const float* __restrict__ I,
                       u16* __restrict__ A) {
    size_t t = (size_t)blockIdx.x * 256 + threadIdx.x;
    size_t base = t * 4;                      // over L*H
    int lrow = (int)(base >> 10);
    int h    = (int)(base & 1023);
    float4 r  = *reinterpret_cast<const float4*>(R + base);
    float4 im = *reinterpret_cast<const float4*>(I + base);
    u16* p0 = A + ((size_t)lrow << 11) + h;
    *reinterpret_cast<ushort4*>(p0) =
        make_ushort4(f2bf(r.x), f2bf(r.y), f2bf(r.z), f2bf(r.w));
    *reinterpret_cast<ushort4*>(p0 + 1024) =
        make_ushort4(f2bf(im.x), f2bf(im.y), f2bf(im.z), f2bf(im.w));
}

// ---------------------------------------------------------------------------
// B_norm pack -> Bp bf16 [2N][2H]
// ---------------------------------------------------------------------------
__global__ void bnorm_pack(const float* __restrict__ Br, const float* __restrict__ Bi,
                           const float* __restrict__ G, u16* __restrict__ Bp) {
    size_t t = (size_t)blockIdx.x * 256 + threadIdx.x;
    size_t base = t * 4;                      // over N*H
    int n = (int)(base >> 10);
    int h = (int)(base & 1023);
    float g = G[n];
    float sg, cg;
    sincosf(g, &sg, &cg);
    float4 br = *reinterpret_cast<const float4*>(Br + base);
    float4 bi = *reinterpret_cast<const float4*>(Bi + base);
    float nr0 = br.x * cg - bi.x * sg, ni0 = br.x * sg + bi.x * cg;
    float nr1 = br.y * cg - bi.y * sg, ni1 = br.y * sg + bi.y * cg;
    float nr2 = br.z * cg - bi.z * sg, ni2 = br.z * sg + bi.z * cg;
    float nr3 = br.w * cg - bi.w * sg, ni3 = br.w * sg + bi.w * cg;
    u16* row0 = Bp + (size_t)n * K2;
    u16* row1 = Bp + (size_t)(N_DIM + n) * K2;
    *reinterpret_cast<ushort4*>(row0 + h) =
        make_ushort4(f2bf(nr0), f2bf(nr1), f2bf(nr2), f2bf(nr3));
    *reinterpret_cast<ushort4*>(row0 + 1024 + h) =
        make_ushort4(f2bf(-ni0), f2bf(-ni1), f2bf(-ni2), f2bf(-ni3));
    *reinterpret_cast<ushort4*>(row1 + h) =
        make_ushort4(f2bf(ni0), f2bf(ni1), f2bf(ni2), f2bf(ni3));
    *reinterpret_cast<ushort4*>(row1 + 1024 + h) =
        make_ushort4(f2bf(nr0), f2bf(nr1), f2bf(nr2), f2bf(nr3));
}

// ---------------------------------------------------------------------------
// C pack -> Cp bf16 [H][2N]: row h = [ C_r[h][:] | -C_i[h][:] ]
// ---------------------------------------------------------------------------
__global__ void pack_C(const float* __restrict__ Cr, const float* __restrict__ Ci,
                       u16* __restrict__ Cp) {
    size_t t = (size_t)blockIdx.x * 256 + threadIdx.x;
    size_t base = t * 4;                      // over H*N
    int h = (int)(base >> 10);
    int n = (int)(base & 1023);
    float4 cr = *reinterpret_cast<const float4*>(Cr + base);
    float4 ci = *reinterpret_cast<const float4*>(Ci + base);
    u16* row = Cp + (size_t)h * K2;
    *reinterpret_cast<ushort4*>(row + n) =
        make_ushort4(f2bf(cr.x), f2bf(cr.y), f2bf(cr.z), f2bf(cr.w));
    *reinterpret_cast<ushort4*>(row + 1024 + n) =
        make_ushort4(f2bf(-ci.x), f2bf(-ci.y), f2bf(-ci.z), f2bf(-ci.w));
}

// ---------------------------------------------------------------------------
// 8-phase deep-pipelined BMx256 bf16 MFMA GEMM (m201 structure).
// BK=64; 8 waves (2M x 4N); per-wave output (WMF*16) x 64.
// LDS per dbuf: A-half0, A-half1 (each BM/2 rows x 128B), B-half0, B-half1
// (each 128 rows x 128B). Tile kt lives in dbuf kt&1.
// A-half h  = rows with qm==h (wave-interleaved stripes); 1-2 gloads.
// B-half h  = rows with qn==h; 2 gloads.
// Quadrant sequence per tile: (0,0),(1,0),(0,1),(1,1); frag reads run ONE
// phase ahead into parity reg sets (aE/aO by qm, bE/bO by qn); A/B halves
// read ONCE per tile. Per phase: {stage 1 half; [vmcnt@p4/p8]; barrier;
// ds-reads (0/4/8/12 b128) || 16 MFMA (setprio); lgkm0; barrier}.
// vmcnt(6) (WMF=8) / vmcnt(4) (WMF=4) = 3 half-tiles in flight; never 0 in
// steady state. 3-bit slot swizzle (slot ^ rr&7), both-sides.
// EPI==0: bf16 store.  EPI==1: OutF = acc + Dv[col]*Ur[row,col].
// ---------------------------------------------------------------------------
template <int EPI, int WMF>
__global__ __launch_bounds__(512, 2) void gemm8p(
    const u16* __restrict__ A, const u16* __restrict__ B, int Klen, int lda,
    u16* __restrict__ OutB, float* __restrict__ OutF, int ldo,
    const float* __restrict__ Dv, const float* __restrict__ Ur) {
    constexpr int BM    = WMF * 32;           // 256 or 128
    constexpr int AMF   = WMF / 2;            // A-frags per quadrant
    constexpr int GA    = BM / 128;           // gloads per A-half (2 or 1)
    constexpr int AH    = (BM / 2) * 128;     // A-half bytes
    constexpr int BH    = 16384;              // B-half bytes
    constexpr int DBUFB = 2 * AH + 2 * BH;
    __shared__ __attribute__((aligned(128))) char lds[2 * DBUFB];
    const int tid = threadIdx.x;
    const int l   = tid & 63;
    const int w   = tid >> 6;
    const int wm  = w >> 2;            // 0..1
    const int wn  = w & 3;             // 0..3
    const long bm = (long)blockIdx.x * BM;
    const long bn = (long)blockIdx.y * 256;

    f32x4 acc[WMF][4];
#pragma unroll
    for (int i = 0; i < WMF; ++i)
#pragma unroll
        for (int j = 0; j < 4; ++j) acc[i][j] = (f32x4){0.f, 0.f, 0.f, 0.f};

    // ---- staging address tables ------------------------------------------
    const int lr  = tid >> 3;
    const int lrh = lr >> 5, lrl = lr & 31;
    const int swzcol = ((tid & 7) ^ (lr & 7)) << 4;
    const size_t rowstride = (size_t)lda * 2;
    const char* Agb = (const char*)A;
    const char* Bgb = (const char*)B;
    size_t a_src[2][GA];
#pragma unroll
    for (int h = 0; h < 2; ++h)
#pragma unroll
        for (int j = 0; j < GA; ++j) {
            int row = (BM == 256) ? (j * 128 + h * 64 + lr)
                                  : (lrh * 64 + h * 32 + lrl);
            a_src[h][j] = (size_t)(bm + row) * rowstride + swzcol;
        }
    size_t b_src[2][2];
#pragma unroll
    for (int h = 0; h < 2; ++h)
#pragma unroll
        for (int j = 0; j < 2; ++j) {
            int row = j * 128 + lrh * 64 + h * 32 + lrl;
            b_src[h][j] = (size_t)(bn + row) * rowstride + swzcol;
        }

    // ---- fragment-read byte offsets (within half-region) -----------------
    const int l15   = l & 15;
    const int lslot = l >> 4;
    int aoff[AMF][2], boff[2][2];
#pragma unroll
    for (int mi = 0; mi < AMF; ++mi)
#pragma unroll
        for (int kk = 0; kk < 2; ++kk) {
            int rr = wm * (BM / 4) + mi * 16 + l15;
            aoff[mi][kk] = rr * 128 + ((((kk << 2) | lslot) ^ (rr & 7)) << 4);
        }
#pragma unroll
    for (int ni = 0; ni < 2; ++ni)
#pragma unroll
        for (int kk = 0; kk < 2; ++kk) {
            int rr = wn * 32 + ni * 16 + l15;
            boff[ni][kk] = rr * 128 + ((((kk << 2) | lslot) ^ (rr & 7)) << 4);
        }

    const int nt    = Klen / 64;
    const int niter = nt / 2;

    bf16x8 aE[2 * AMF], aO[2 * AMF], bE[4], bO[4];

#define STAGE_A(KT, H) do { if ((KT) < nt) {                                 \
    char* _d = lds + ((KT) & 1) * DBUFB + (H) * AH + tid * 16;               \
    _Pragma("unroll") for (int j = 0; j < GA; ++j)                           \
        gload_lds16(Agb + a_src[H][j] + (size_t)(KT) * 128, _d + j * 8192);  \
    } } while (0)
#define STAGE_B(KT, H) do { if ((KT) < nt) {                                 \
    char* _d = lds + ((KT) & 1) * DBUFB + 2 * AH + (H) * BH + tid * 16;      \
    _Pragma("unroll") for (int j = 0; j < 2; ++j)                            \
        gload_lds16(Bgb + b_src[H][j] + (size_t)(KT) * 128, _d + j * 8192);  \
    } } while (0)
#define READ_A(DST, QM, DB) {                                                \
    _Pragma("unroll") for (int mi = 0; mi < AMF; ++mi)                       \
        _Pragma("unroll") for (int kk = 0; kk < 2; ++kk)                     \
            DST[mi * 2 + kk] = *reinterpret_cast<const bf16x8*>(             \
                lds + (DB) * DBUFB + (QM) * AH + aoff[mi][kk]); }
#define READ_B(DST, QN, DB) {                                                \
    _Pragma("unroll") for (int ni = 0; ni < 2; ++ni)                         \
        _Pragma("unroll") for (int kk = 0; kk < 2; ++kk)                     \
            DST[ni * 2 + kk] = *reinterpret_cast<const bf16x8*>(             \
                lds + (DB) * DBUFB + 2 * AH + (QN) * BH + boff[ni][kk]); }
#define MFMA_Q(ASET, BSET, QM, QN) {                                         \
    __builtin_amdgcn_s_setprio(1);                                           \
    _Pragma("unroll") for (int mi = 0; mi < AMF; ++mi)                       \
        _Pragma("unroll") for (int ni = 0; ni < 2; ++ni)                     \
            _Pragma("unroll") for (int kk = 0; kk < 2; ++kk)                 \
                acc[(QM) * AMF + mi][(QN) * 2 + ni] =                        \
                    __builtin_amdgcn_mfma_f32_16x16x32_bf16(                 \
                        ASET[mi * 2 + kk], BSET[ni * 2 + kk],                \
                        acc[(QM) * AMF + mi][(QN) * 2 + ni], 0, 0, 0);       \
    __builtin_amdgcn_s_setprio(0); }
#define VMW do { if constexpr (WMF == 8)                                     \
        asm volatile("s_waitcnt vmcnt(6)" ::: "memory");                     \
    else asm volatile("s_waitcnt vmcnt(4)" ::: "memory"); } while (0)
#define BAR1 do { __builtin_amdgcn_sched_barrier(0);                         \
    __builtin_amdgcn_s_barrier();                                            \
    __builtin_amdgcn_sched_barrier(0); } while (0)
#define ENDPH do { asm volatile("s_waitcnt lgkmcnt(0)" ::: "memory");        \
    __builtin_amdgcn_sched_barrier(0);                                       \
    __builtin_amdgcn_s_barrier();                                            \
    __builtin_amdgcn_sched_barrier(0); } while (0)

    // ---- prologue: tile0 fully + tile1 {B0,A0,A1}; B1(1) staged at p1 ----
    STAGE_B(0, 0); STAGE_A(0, 0); STAGE_A(0, 1); STAGE_B(0, 1);
    STAGE_B(1, 0); STAGE_A(1, 0); STAGE_A(1, 1);
    VMW;
    BAR1;
    READ_A(aE, 0, 0); READ_B(bE, 0, 0);
    asm volatile("s_waitcnt lgkmcnt(0)" ::: "memory");

    for (int i = 0; i < niter; ++i) {
        const int t2 = 2 * i;
        // p1: Q(0,0) T0/db0 | stage B1(t2+1)->db1 | read A1(T0)->aO
        STAGE_B(t2 + 1, 1);
        BAR1;
        READ_A(aO, 1, 0);
        MFMA_Q(aE, bE, 0, 0);
        ENDPH;
        // p2: Q(1,0) db0 | stage B0(t2+2)->db0 | read B1(T0)->bO
        STAGE_B(t2 + 2, 0);
        BAR1;
        READ_B(bO, 1, 0);
        MFMA_Q(aO, bE, 1, 0);
        ENDPH;
        // p3: Q(0,1) db0 | stage A0(t2+2)
        STAGE_A(t2 + 2, 0);
        BAR1;
        MFMA_Q(aE, bO, 0, 1);
        ENDPH;
        // p4: Q(1,1) db0 | stage A1(t2+2) | vmcnt | read A0,B0(T1)->aE,bE
        STAGE_A(t2 + 2, 1);
        if (i + 1 < niter) { VMW; }
        else { asm volatile("s_waitcnt vmcnt(0)" ::: "memory"); }
        BAR1;
        READ_A(aE, 0, 1); READ_B(bE, 0, 1);
        MFMA_Q(aO, bO, 1, 1);
        ENDPH;
        // p5: Q(0,0) T1/db1 | stage B1(t2+2)->db0 | read A1(T1)->aO
        STAGE_B(t2 + 2, 1);
        BAR1;
        READ_A(aO, 1, 1);
        MFMA_Q(aE, bE, 0, 0);
        ENDPH;
        // p6: Q(1,0) db1 | stage B0(t2+3)->db1 | read B1(T1)->bO
        STAGE_B(t2 + 3, 0);
        BAR1;
        READ_B(bO, 1, 1);
        MFMA_Q(aO, bE, 1, 0);
        ENDPH;
        // p7: Q(0,1) db1 | stage A0(t2+3)
        STAGE_A(t2 + 3, 0);
        BAR1;
        MFMA_Q(aE, bO, 0, 1);
        ENDPH;
        // p8: Q(1,1) db1 | stage A1(t2+3) | vmcnt | read A0,B0(t2+2)->aE,bE
        STAGE_A(t2 + 3, 1);
        VMW;
        BAR1;
        if (i + 1 < niter) { READ_A(aE, 0, 0); READ_B(bE, 0, 0); }
        MFMA_Q(aO, bO, 1, 1);
        ENDPH;
    }

#undef STAGE_A
#undef STAGE_B
#undef READ_A
#undef READ_B
#undef MFMA_Q
#undef VMW
#undef BAR1
#undef ENDPH

    // ---- epilogue: C/D layout col = lane&15, row = (lane>>4)*4 + reg ------
#pragma unroll
    for (int mi = 0; mi < WMF; ++mi) {
        const long row0 = bm + wm * (WMF * 16) + mi * 16 + ((l >> 4) << 2);
#pragma unroll
        for (int ni = 0; ni < 4; ++ni) {
            const long col = bn + wn * 64 + ni * 16 + l15;
            if (EPI == 0) {
#pragma unroll
                for (int r = 0; r < 4; ++r)
                    OutB[(size_t)(row0 + r) * ldo + col] = f2bf(acc[mi][ni][r]);
            } else {
                const float d = Dv[col];
#pragma unroll
                for (int r = 0; r < 4; ++r) {
                    size_t o = (size_t)(row0 + r) * ldo + col;
                    OutF[o] = acc[mi][ni][r] + d * Ur[o];
                }
            }
        }
    }
}

// ---------------------------------------------------------------------------
// Scan pass A: per-(chunk, channel) local scan in fp32 state over bf16 X.
// ---------------------------------------------------------------------------
__global__ void scan_local(u16* __restrict__ X,
                           const float* __restrict__ Lr, const float* __restrict__ Li,
                           float* __restrict__ Acr, float* __restrict__ Aci,
                           float* __restrict__ bcr, float* __restrict__ bci) {
    int n = blockIdx.y * 256 + threadIdx.x;   // 0..1023
    int c = blockIdx.x;
    float lr = Lr[n], li = Li[n];
    float sr = 0.f, si = 0.f, pr = 1.f, pi = 0.f;
    size_t base = (size_t)c * CHUNK * K2 + n;
    for (int j = 0; j < CHUNK; ++j) {
        size_t idx = base + (size_t)j * K2;
        float br = bf2f(X[idx]), bi = bf2f(X[idx + 1024]);
        float nr = lr * sr - li * si + br;
        float ni = lr * si + li * sr + bi;
        sr = nr; si = ni;
        X[idx] = f2bf(sr); X[idx + 1024] = f2bf(si);
        float qr = lr * pr - li * pi;
        float qi = lr * pi + li * pr;
        pr = qr; pi = qi;
    }
    Acr[c * N_DIM + n] = pr; Aci[c * N_DIM + n] = pi;
    bcr[c * N_DIM + n] = sr; bci[c * N_DIM + n] = si;
}

// ---------------------------------------------------------------------------
// Scan pass B: sequential scan over NCHUNK chunk summaries (fp32).
// ---------------------------------------------------------------------------
__global__ void scan_carry(const float* __restrict__ Acr, const float* __restrict__ Aci,
                           const float* __restrict__ bcr, const float* __restrict__ bci,
                           float* __restrict__ car, float* __restrict__ cai) {
    int n = blockIdx.x * 256 + threadIdx.x;
    float sr = 0.f, si = 0.f;
    for (int c = 0; c < NCHUNK; ++c) {
        car[c * N_DIM + n] = sr; cai[c * N_DIM + n] = si;
        float ar = Acr[c * N_DIM + n], ai = Aci[c * N_DIM + n];
        float nr = ar * sr - ai * si + bcr[c * N_DIM + n];
        float ni = ar * si + ai * sr + bci[c * N_DIM + n];
        sr = nr; si = ni;
    }
}

// ---------------------------------------------------------------------------
// Scan pass C: X[c*CHUNK+j] += Lambda^(j+1) * carry_in[c]   (bf16 RMW)
// ---------------------------------------------------------------------------
__global__ void scan_fix(u16* __restrict__ X,
                         const float* __restrict__ Lr, const float* __restrict__ Li,
                         const float* __restrict__ car, const float* __restrict__ cai) {
    int n = blockIdx.y * 256 + threadIdx.x;
    int c = blockIdx.x + 1;
    float lr = Lr[n], li = Li[n];
    float cr = car[c * N_DIM + n], ci = cai[c * N_DIM + n];
    float pr = lr * cr - li * ci;
    float pi = lr * ci + li * cr;
    size_t base = (size_t)c * CHUNK * K2 + n;
    for (int j = 0; j < CHUNK; ++j) {
        size_t idx = base + (size_t)j * K2;
        X[idx]        = f2bf(bf2f(X[idx]) + pr);
        X[idx + 1024] = f2bf(bf2f(X[idx + 1024]) + pi);
        float qr = lr * pr - li * pi;
        float qi = lr * pi + li * pr;
        pr = qr; pi = qi;
    }
}

// ---------------------------------------------------------------------------
// Launch
// ---------------------------------------------------------------------------
extern "C" void kernel_launch(void* const* d_in, const int* in_sizes, int n_in,
                              void* d_out, int out_size, void* d_ws, size_t ws_size,
                              hipStream_t stream) {
    (void)in_sizes; (void)n_in; (void)out_size; (void)ws_size;
    const float* input_real = (const float*)d_in[0];
    const float* input_imag = (const float*)d_in[1];
    const float* nu_log     = (const float*)d_in[2];
    const float* theta_log  = (const float*)d_in[3];
    const float* B_real     = (const float*)d_in[4];
    const float* B_imag     = (const float*)d_in[5];
    const float* C_real     = (const float*)d_in[6];
    const float* C_imag     = (const float*)d_in[7];
    const float* D          = (const float*)d_in[8];
    const float* gamma_log  = (const float*)d_in[9];
    float* y = (float*)d_out;

    // Workspace layout (bytes):
    // [0, 4K)    Lr    [4K, 8K)   Li
    // [8K, ~1.5M)  Acr/Aci/bcr/bci/car/cai (6 x 256KB)
    // [2M, 34M)  A' bf16 [8192][2048]  (dead after gemm1)
    //   [2M, 6M)   Cp aliases A' head  (alive after pack_C)
    // [34M, 42M) Bp bf16 [2048][2048]  (dead after gemm1)
    // [42M, 74M) X  bf16 [8192][2048]  (Bu -> x in place)
    char* ws = (char*)d_ws;
    float* Lr  = (float*)(ws);
    float* Li  = (float*)(ws + (4 << 10));
    float* Acr = (float*)(ws + (8 << 10));
    float* Aci = Acr + NCHUNK * N_DIM;
    float* bcr = Aci + NCHUNK * N_DIM;
    float* bci = bcr + NCHUNK * N_DIM;
    float* car = bci + NCHUNK * N_DIM;
    float* cai = car + NCHUNK * N_DIM;
    u16* Ap   = (u16*)(ws + ((size_t)2 << 20));
    u16* Cp   = Ap;                                 // alias: used only after gemm1
    u16* Bp   = (u16*)(ws + ((size_t)34 << 20));
    u16* X    = (u16*)(ws + ((size_t)42 << 20));

    lru_lambda<<<N_DIM / 256, 256, 0, stream>>>(nu_log, theta_log, Lr, Li);
    pack_u<<<(L_SEQ * H_DIM / 4) / 256, 256, 0, stream>>>(input_real, input_imag, Ap);
    bnorm_pack<<<(N_DIM * H_DIM / 4) / 256, 256, 0, stream>>>(B_real, B_imag, gamma_log, Bp);
    // GEMM1: 256x256 tile, grid 32x8 = 256 blocks (1/CU), K=2048
    gemm8p<0, 8><<<dim3(L_SEQ / 256, K2 / 256), 512, 0, stream>>>(
        Ap, Bp, K2, K2, X, nullptr, K2, nullptr, nullptr);
    scan_local<<<dim3(NCHUNK, N_DIM / 256), 256, 0, stream>>>(X, Lr, Li, Acr, Aci, bcr, bci);
    scan_carry<<<N_DIM / 256, 256, 0, stream>>>(Acr, Aci, bcr, bci, car, cai);
    scan_fix<<<dim3(NCHUNK - 1, N_DIM / 256), 256, 0, stream>>>(X, Lr, Li, car, cai);
    pack_C<<<(H_DIM * N_DIM / 4) / 256, 256, 0, stream>>>(C_real, C_imag, Cp);
    // GEMM2: 128x256 tile, grid 64x4 = 256 blocks (1/CU), K=2048, fused D*u
    gemm8p<1, 4><<<dim3(L_SEQ / 128, H_DIM / 256), 512, 0, stream>>>(
        X, Cp, K2, K2, nullptr, y, H_DIM, D, input_real);
}

// Round 8
// 171.817 us; speedup vs baseline: 1.0914x; 1.0914x over previous
//
#include <hip/hip_runtime.h>
#include <math.h>

#define L_SEQ 8192
#define H_DIM 1024
#define N_DIM 1024
#define K2    2048          // packed K = 2*H = 2*N
#define NCHUNK 64
#define CHUNK 128

typedef unsigned short u16;
typedef __attribute__((ext_vector_type(8))) __bf16 bf16x8;
typedef __attribute__((ext_vector_type(4))) float  f32x4;

__device__ __forceinline__ u16 f2bf(float x) {
    unsigned int u = __float_as_uint(x);
    u = (u + 0x7fffu + ((u >> 16) & 1u)) >> 16;   // RNE
    return (u16)u;
}
__device__ __forceinline__ float bf2f(u16 h) {
    return __uint_as_float(((unsigned int)h) << 16);
}

__device__ __forceinline__ void gload_lds16(const void* g, void* s) {
    __builtin_amdgcn_global_load_lds(
        (const __attribute__((address_space(1))) unsigned int*)g,
        (__attribute__((address_space(3))) unsigned int*)s, 16, 0, 0);
}

// ---------------------------------------------------------------------------
// Pack u -> A' bf16 [L][2H]: cols [0,1024)=u_r, [1024,2048)=u_i
// ---------------------------------------------------------------------------
__global__ void pack_u(const float* __restrict__ R, const float* __restrict__ I,
                       u16* __restrict__ A) {
    size_t t = (size_t)blockIdx.x * 256 + threadIdx.x;
    size_t base = t * 4;                      // over L*H
    int lrow = (int)(base >> 10);
    int h    = (int)(base & 1023);
    float4 r  = *reinterpret_cast<const float4*>(R + base);
    float4 im = *reinterpret_cast<const float4*>(I + base);
    u16* p0 = A + ((size_t)lrow << 11) + h;
    *reinterpret_cast<ushort4*>(p0) =
        make_ushort4(f2bf(r.x), f2bf(r.y), f2bf(r.z), f2bf(r.w));
    *reinterpret_cast<ushort4*>(p0 + 1024) =
        make_ushort4(f2bf(im.x), f2bf(im.y), f2bf(im.z), f2bf(im.w));
}

// ---------------------------------------------------------------------------
// B_norm pack -> Bp bf16 [2N][2H]
// ---------------------------------------------------------------------------
__global__ void bnorm_pack(const float* __restrict__ Br, const float* __restrict__ Bi,
                           const float* __restrict__ G, u16* __restrict__ Bp) {
    size_t t = (size_t)blockIdx.x * 256 + threadIdx.x;
    size_t base = t * 4;                      // over N*H
    int n = (int)(base >> 10);
    int h = (int)(base & 1023);
    float g = G[n];
    float sg, cg;
    sincosf(g, &sg, &cg);
    float4 br = *reinterpret_cast<const float4*>(Br + base);
    float4 bi = *reinterpret_cast<const float4*>(Bi + base);
    float nr0 = br.x * cg - bi.x * sg, ni0 = br.x * sg + bi.x * cg;
    float nr1 = br.y * cg - bi.y * sg, ni1 = br.y * sg + bi.y * cg;
    float nr2 = br.z * cg - bi.z * sg, ni2 = br.z * sg + bi.z * cg;
    float nr3 = br.w * cg - bi.w * sg, ni3 = br.w * sg + bi.w * cg;
    u16* row0 = Bp + (size_t)n * K2;
    u16* row1 = Bp + (size_t)(N_DIM + n) * K2;
    *reinterpret_cast<ushort4*>(row0 + h) =
        make_ushort4(f2bf(nr0), f2bf(nr1), f2bf(nr2), f2bf(nr3));
    *reinterpret_cast<ushort4*>(row0 + 1024 + h) =
        make_ushort4(f2bf(-ni0), f2bf(-ni1), f2bf(-ni2), f2bf(-ni3));
    *reinterpret_cast<ushort4*>(row1 + h) =
        make_ushort4(f2bf(ni0), f2bf(ni1), f2bf(ni2), f2bf(ni3));
    *reinterpret_cast<ushort4*>(row1 + 1024 + h) =
        make_ushort4(f2bf(nr0), f2bf(nr1), f2bf(nr2), f2bf(nr3));
}

// ---------------------------------------------------------------------------
// C pack -> Cp bf16 [H][2N]: row h = [ C_r[h][:] | -C_i[h][:] ]
// ---------------------------------------------------------------------------
__global__ void pack_C(const float* __restrict__ Cr, const float* __restrict__ Ci,
                       u16* __restrict__ Cp) {
    size_t t = (size_t)blockIdx.x * 256 + threadIdx.x;
    size_t base = t * 4;                      // over H*N
    int h = (int)(base >> 10);
    int n = (int)(base & 1023);
    float4 cr = *reinterpret_cast<const float4*>(Cr + base);
    float4 ci = *reinterpret_cast<const float4*>(Ci + base);
    u16* row = Cp + (size_t)h * K2;
    *reinterpret_cast<ushort4*>(row + n) =
        make_ushort4(f2bf(cr.x), f2bf(cr.y), f2bf(cr.z), f2bf(cr.w));
    *reinterpret_cast<ushort4*>(row + 1024 + n) =
        make_ushort4(f2bf(-ci.x), f2bf(-ci.y), f2bf(-ci.z), f2bf(-ci.w));
}

// ---------------------------------------------------------------------------
// GEMM1 (round-5 proven): 256x256 tile, BK=64, 8 waves (2Mx4N), dbuf K-tiles,
// counted vmcnt (never 0 in steady state), 3-bit slot swizzle both-sides.
// Out = A*B^T, bf16 store.
// ---------------------------------------------------------------------------
__global__ __launch_bounds__(512, 2) void gemm_pipe(
    const u16* __restrict__ A, const u16* __restrict__ B, int Klen, int lda,
    u16* __restrict__ OutB, int ldo) {
    constexpr int BM     = 256;
    constexpr int ABYTES = BM * 128;
    constexpr int SLOT   = (BM + 256) * 128;
    __shared__ __attribute__((aligned(128))) char lds[2 * SLOT];
    const int tid = threadIdx.x;
    const int l   = tid & 63;
    const int w   = tid >> 6;
    const int wm  = w >> 2;
    const int wn  = w & 3;
    const long bm = (long)blockIdx.x * BM;
    const long bn = (long)blockIdx.y * 256;

    f32x4 acc[8][4];
#pragma unroll
    for (int i = 0; i < 8; ++i)
#pragma unroll
        for (int j = 0; j < 4; ++j) acc[i][j] = (f32x4){0.f, 0.f, 0.f, 0.f};

    const int    swzcol    = (((tid & 7) ^ ((tid >> 3) & 7)) << 4);
    const size_t rowstride = (size_t)lda * 2;
    const size_t a_src0    = (size_t)(bm + (tid >> 3)) * rowstride + swzcol;
    const size_t b_src0    = (size_t)(bn + (tid >> 3)) * rowstride + swzcol;
    const char*  Agb       = (const char*)A;
    const char*  Bgb       = (const char*)B;

    auto STAGE = [&](int kt, int sl) {
        const size_t kofs = (size_t)kt * 128;
        char* la = lds + sl * SLOT + tid * 16;
        char* lb = lds + sl * SLOT + ABYTES + tid * 16;
#pragma unroll
        for (int j = 0; j < 4; ++j)
            gload_lds16(Agb + a_src0 + (size_t)j * 64 * rowstride + kofs,
                        la + j * 8192);
#pragma unroll
        for (int j = 0; j < 4; ++j)
            gload_lds16(Bgb + b_src0 + (size_t)j * 64 * rowstride + kofs,
                        lb + j * 8192);
    };

    const int l15   = l & 15;
    const int lslot = l >> 4;

    const int nt = Klen / 64;
    STAGE(0, 0);
    STAGE(1, 1);

    for (int t = 0; t < nt; ++t) {
        const int s = t & 1;
        if (t < nt - 1) asm volatile("s_waitcnt vmcnt(8)" ::: "memory");
        else            asm volatile("s_waitcnt vmcnt(0)" ::: "memory");
        __builtin_amdgcn_sched_barrier(0);
        __builtin_amdgcn_s_barrier();       // K-tile t resident for all waves
        __builtin_amdgcn_sched_barrier(0);

        const char* lA = lds + s * SLOT;
        const char* lB = lA + ABYTES;
#pragma unroll
        for (int kk = 0; kk < 2; ++kk) {
            bf16x8 af[8], bg[4];
#pragma unroll
            for (int mi = 0; mi < 8; ++mi) {
                int r   = wm * 128 + mi * 16 + l15;
                int sl3 = ((kk << 2) | lslot) ^ (r & 7);
                af[mi]  = *reinterpret_cast<const bf16x8*>(lA + r * 128 + sl3 * 16);
            }
#pragma unroll
            for (int ni = 0; ni < 4; ++ni) {
                int r   = wn * 64 + ni * 16 + l15;
                int sl3 = ((kk << 2) | lslot) ^ (r & 7);
                bg[ni]  = *reinterpret_cast<const bf16x8*>(lB + r * 128 + sl3 * 16);
            }
            __builtin_amdgcn_s_setprio(1);
#pragma unroll
            for (int mi = 0; mi < 8; ++mi)
#pragma unroll
                for (int ni = 0; ni < 4; ++ni)
                    acc[mi][ni] = __builtin_amdgcn_mfma_f32_16x16x32_bf16(
                        af[mi], bg[ni], acc[mi][ni], 0, 0, 0);
            __builtin_amdgcn_s_setprio(0);
        }
        __builtin_amdgcn_sched_barrier(0);
        __builtin_amdgcn_s_barrier();       // all waves done reading slot s
        __builtin_amdgcn_sched_barrier(0);
        if (t + 2 < nt) STAGE(t + 2, s);
    }

    // C/D layout: col = lane&15, row = (lane>>4)*4 + reg
#pragma unroll
    for (int mi = 0; mi < 8; ++mi) {
        const long row0 = bm + wm * 128 + mi * 16 + ((l >> 4) << 2);
#pragma unroll
        for (int ni = 0; ni < 4; ++ni) {
            const long col = bn + wn * 64 + ni * 16 + l15;
#pragma unroll
            for (int r = 0; r < 4; ++r)
                OutB[(size_t)(row0 + r) * ldo + col] = f2bf(acc[mi][ni][r]);
        }
    }
}

// ---------------------------------------------------------------------------
// GEMM2: 128x128 tile, BK=64, 256 threads (4 waves 2Mx2N), 64KB LDS ->
// 2 blocks/CU; two async blocks fill each other's stage/barrier bubbles.
// Same dbuf + counted-vmcnt loop + 3-bit slot swizzle. Fused epilogue:
// OutF = acc + Dv[col] * Ur[row,col].
// ---------------------------------------------------------------------------
__global__ __launch_bounds__(256, 2) void gemm_small(
    const u16* __restrict__ A, const u16* __restrict__ B, int Klen, int lda,
    float* __restrict__ OutF, int ldo,
    const float* __restrict__ Dv, const float* __restrict__ Ur) {
    constexpr int ABYTES = 128 * 128;          // 16KB
    constexpr int SLOT   = 2 * ABYTES;         // 32KB (A+B)
    __shared__ __attribute__((aligned(128))) char lds[2 * SLOT];  // 64KB
    const int tid = threadIdx.x;
    const int l   = tid & 63;
    const int w   = tid >> 6;          // 0..3
    const int wm  = w >> 1;            // 0..1
    const int wn  = w & 1;             // 0..1
    const long bm = (long)blockIdx.x * 128;
    const long bn = (long)blockIdx.y * 128;

    f32x4 acc[4][4];
#pragma unroll
    for (int i = 0; i < 4; ++i)
#pragma unroll
        for (int j = 0; j < 4; ++j) acc[i][j] = (f32x4){0.f, 0.f, 0.f, 0.f};

    // staging: one gload = 256 thr x 16B = 4KB = 32 rows; 4 gloads per side
    const int    lr        = tid >> 3;                    // 0..31
    const int    swzcol    = (((tid & 7) ^ (lr & 7)) << 4);
    const size_t rowstride = (size_t)lda * 2;
    const size_t a_src0    = (size_t)(bm + lr) * rowstride + swzcol;
    const size_t b_src0    = (size_t)(bn + lr) * rowstride + swzcol;
    const char*  Agb       = (const char*)A;
    const char*  Bgb       = (const char*)B;

    auto STAGE = [&](int kt, int sl) {
        const size_t kofs = (size_t)kt * 128;
        char* la = lds + sl * SLOT + tid * 16;
        char* lb = lds + sl * SLOT + ABYTES + tid * 16;
#pragma unroll
        for (int j = 0; j < 4; ++j)
            gload_lds16(Agb + a_src0 + (size_t)j * 32 * rowstride + kofs,
                        la + j * 4096);
#pragma unroll
        for (int j = 0; j < 4; ++j)
            gload_lds16(Bgb + b_src0 + (size_t)j * 32 * rowstride + kofs,
                        lb + j * 4096);
    };

    const int l15   = l & 15;
    const int lslot = l >> 4;

    const int nt = Klen / 64;
    STAGE(0, 0);
    STAGE(1, 1);

    for (int t = 0; t < nt; ++t) {
        const int s = t & 1;
        if (t < nt - 1) asm volatile("s_waitcnt vmcnt(8)" ::: "memory");
        else            asm volatile("s_waitcnt vmcnt(0)" ::: "memory");
        __builtin_amdgcn_sched_barrier(0);
        __builtin_amdgcn_s_barrier();
        __builtin_amdgcn_sched_barrier(0);

        const char* lA = lds + s * SLOT;
        const char* lB = lA + ABYTES;
#pragma unroll
        for (int kk = 0; kk < 2; ++kk) {
            bf16x8 af[4], bg[4];
#pragma unroll
            for (int mi = 0; mi < 4; ++mi) {
                int r   = wm * 64 + mi * 16 + l15;
                int sl3 = ((kk << 2) | lslot) ^ (r & 7);
                af[mi]  = *reinterpret_cast<const bf16x8*>(lA + r * 128 + sl3 * 16);
            }
#pragma unroll
            for (int ni = 0; ni < 4; ++ni) {
                int r   = wn * 64 + ni * 16 + l15;
                int sl3 = ((kk << 2) | lslot) ^ (r & 7);
                bg[ni]  = *reinterpret_cast<const bf16x8*>(lB + r * 128 + sl3 * 16);
            }
            __builtin_amdgcn_s_setprio(1);
#pragma unroll
            for (int mi = 0; mi < 4; ++mi)
#pragma unroll
                for (int ni = 0; ni < 4; ++ni)
                    acc[mi][ni] = __builtin_amdgcn_mfma_f32_16x16x32_bf16(
                        af[mi], bg[ni], acc[mi][ni], 0, 0, 0);
            __builtin_amdgcn_s_setprio(0);
        }
        __builtin_amdgcn_sched_barrier(0);
        __builtin_amdgcn_s_barrier();
        __builtin_amdgcn_sched_barrier(0);
        if (t + 2 < nt) STAGE(t + 2, s);
    }

    // epilogue with fused D*u_r
#pragma unroll
    for (int mi = 0; mi < 4; ++mi) {
        const long row0 = bm + wm * 64 + mi * 16 + ((l >> 4) << 2);
#pragma unroll
        for (int ni = 0; ni < 4; ++ni) {
            const long col = bn + wn * 64 + ni * 16 + l15;
            const float d = Dv[col];
#pragma unroll
            for (int r = 0; r < 4; ++r) {
                size_t o = (size_t)(row0 + r) * ldo + col;
                OutF[o] = acc[mi][ni][r] + d * Ur[o];
            }
        }
    }
}

// ---------------------------------------------------------------------------
// Scan pass A (read-only): per-(chunk, channel) summaries.
// A_c = Lambda^CHUNK, b_c = local final state (zero-init). Lambda inline.
// ---------------------------------------------------------------------------
__global__ void scan_sum(const u16* __restrict__ X,
                         const float* __restrict__ nu_log,
                         const float* __restrict__ theta_log,
                         float* __restrict__ Acr, float* __restrict__ Aci,
                         float* __restrict__ bcr, float* __restrict__ bci) {
    int n = blockIdx.y * 256 + threadIdx.x;   // 0..1023
    int c = blockIdx.x;
    float mag = expf(-expf(nu_log[n]));
    float th  = expf(theta_log[n]);
    float sg, cg;
    sincosf(th, &sg, &cg);
    float lr = mag * cg, li = mag * sg;
    float sr = 0.f, si = 0.f, pr = 1.f, pi = 0.f;
    size_t base = (size_t)c * CHUNK * K2 + n;
    for (int j = 0; j < CHUNK; ++j) {
        size_t idx = base + (size_t)j * K2;
        float br = bf2f(X[idx]), bi = bf2f(X[idx + 1024]);
        float nr = lr * sr - li * si + br;
        float ni = lr * si + li * sr + bi;
        sr = nr; si = ni;
        float qr = lr * pr - li * pi;
        float qi = lr * pi + li * pr;
        pr = qr; pi = qi;
    }
    Acr[c * N_DIM + n] = pr; Aci[c * N_DIM + n] = pi;
    bcr[c * N_DIM + n] = sr; bci[c * N_DIM + n] = si;
}

// ---------------------------------------------------------------------------
// Scan pass B: sequential scan over NCHUNK chunk summaries (fp32).
// car[c] = exact state entering chunk c (car[0] = 0).
// ---------------------------------------------------------------------------
__global__ void scan_carry(const float* __restrict__ Acr, const float* __restrict__ Aci,
                           const float* __restrict__ bcr, const float* __restrict__ bci,
                           float* __restrict__ car, float* __restrict__ cai) {
    int n = blockIdx.x * 256 + threadIdx.x;
    float sr = 0.f, si = 0.f;
    for (int c = 0; c < NCHUNK; ++c) {
        car[c * N_DIM + n] = sr; cai[c * N_DIM + n] = si;
        float ar = Acr[c * N_DIM + n], ai = Aci[c * N_DIM + n];
        float nr = ar * sr - ai * si + bcr[c * N_DIM + n];
        float ni = ar * si + ai * sr + bci[c * N_DIM + n];
        sr = nr; si = ni;
    }
}

// ---------------------------------------------------------------------------
// Scan pass C: re-scan each chunk seeded with its exact carry-in; write
// final x (bf16, in place over Bu). fp32 state end-to-end.
// ---------------------------------------------------------------------------
__global__ void scan_apply(u16* __restrict__ X,
                           const float* __restrict__ nu_log,
                           const float* __restrict__ theta_log,
                           const float* __restrict__ car, const float* __restrict__ cai) {
    int n = blockIdx.y * 256 + threadIdx.x;
    int c = blockIdx.x;
    float mag = expf(-expf(nu_log[n]));
    float th  = expf(theta_log[n]);
    float sg, cg;
    sincosf(th, &sg, &cg);
    float lr = mag * cg, li = mag * sg;
    float sr = car[c * N_DIM + n], si = cai[c * N_DIM + n];
    size_t base = (size_t)c * CHUNK * K2 + n;
    for (int j = 0; j < CHUNK; ++j) {
        size_t idx = base + (size_t)j * K2;
        float br = bf2f(X[idx]), bi = bf2f(X[idx + 1024]);
        float nr = lr * sr - li * si + br;
        float ni = lr * si + li * sr + bi;
        sr = nr; si = ni;
        X[idx] = f2bf(sr); X[idx + 1024] = f2bf(si);
    }
}

// ---------------------------------------------------------------------------
// Launch
// ---------------------------------------------------------------------------
extern "C" void kernel_launch(void* const* d_in, const int* in_sizes, int n_in,
                              void* d_out, int out_size, void* d_ws, size_t ws_size,
                              hipStream_t stream) {
    (void)in_sizes; (void)n_in; (void)out_size; (void)ws_size;
    const float* input_real = (const float*)d_in[0];
    const float* input_imag = (const float*)d_in[1];
    const float* nu_log     = (const float*)d_in[2];
    const float* theta_log  = (const float*)d_in[3];
    const float* B_real     = (const float*)d_in[4];
    const float* B_imag     = (const float*)d_in[5];
    const float* C_real     = (const float*)d_in[6];
    const float* C_imag     = (const float*)d_in[7];
    const float* D          = (const float*)d_in[8];
    const float* gamma_log  = (const float*)d_in[9];
    float* y = (float*)d_out;

    // Workspace layout (bytes):
    // [8K, ~1.6M)  Acr/Aci/bcr/bci/car/cai (6 x 256KB)
    // [2M, 34M)  A' bf16 [8192][2048]  (dead after gemm1)
    //   [2M, 6M)   Cp aliases A' head  (alive after pack_C)
    // [34M, 42M) Bp bf16 [2048][2048]  (dead after gemm1)
    // [42M, 74M) X  bf16 [8192][2048]  (Bu -> x in place)
    char* ws = (char*)d_ws;
    float* Acr = (float*)(ws + (8 << 10));
    float* Aci = Acr + NCHUNK * N_DIM;
    float* bcr = Aci + NCHUNK * N_DIM;
    float* bci = bcr + NCHUNK * N_DIM;
    float* car = bci + NCHUNK * N_DIM;
    float* cai = car + NCHUNK * N_DIM;
    u16* Ap   = (u16*)(ws + ((size_t)2 << 20));
    u16* Cp   = Ap;                                 // alias: used only after gemm1
    u16* Bp   = (u16*)(ws + ((size_t)34 << 20));
    u16* X    = (u16*)(ws + ((size_t)42 << 20));

    pack_u<<<(L_SEQ * H_DIM / 4) / 256, 256, 0, stream>>>(input_real, input_imag, Ap);
    bnorm_pack<<<(N_DIM * H_DIM / 4) / 256, 256, 0, stream>>>(B_real, B_imag, gamma_log, Bp);
    // GEMM1: 256x256 tile, grid 32x8 = 256 blocks (1/CU), K=2048
    gemm_pipe<<<dim3(L_SEQ / 256, K2 / 256), 512, 0, stream>>>(
        Ap, Bp, K2, K2, X, K2);
    scan_sum<<<dim3(NCHUNK, N_DIM / 256), 256, 0, stream>>>(
        X, nu_log, theta_log, Acr, Aci, bcr, bci);
    scan_carry<<<N_DIM / 256, 256, 0, stream>>>(Acr, Aci, bcr, bci, car, cai);
    scan_apply<<<dim3(NCHUNK, N_DIM / 256), 256, 0, stream>>>(
        X, nu_log, theta_log, car, cai);
    pack_C<<<(H_DIM * N_DIM / 4) / 256, 256, 0, stream>>>(C_real, C_imag, Cp);
    // GEMM2: 128x128 tile, grid 64x8 = 512 blocks (2/CU), K=2048, fused D*u
    gemm_small<<<dim3(L_SEQ / 128, H_DIM / 128), 256, 0, stream>>>(
        X, Cp, K2, K2, y, H_DIM, D, input_real);
}

// Round 10
// 170.720 us; speedup vs baseline: 1.0984x; 1.0064x over previous
//
#include <hip/hip_runtime.h>
#include <math.h>

#define L_SEQ 8192
#define H_DIM 1024
#define N_DIM 1024
#define K2    2048          // packed K = 2*H = 2*N
#define NCHUNK 256
#define CHUNK 32

typedef unsigned short u16;
typedef __attribute__((ext_vector_type(8))) __bf16 bf16x8;
typedef __attribute__((ext_vector_type(4))) float  f32x4;

__device__ __forceinline__ u16 f2bf(float x) {
    unsigned int u = __float_as_uint(x);
    u = (u + 0x7fffu + ((u >> 16) & 1u)) >> 16;   // RNE
    return (u16)u;
}
__device__ __forceinline__ float bf2f(u16 h) {
    return __uint_as_float(((unsigned int)h) << 16);
}

__device__ __forceinline__ void gload_lds16(const void* g, void* s) {
    __builtin_amdgcn_global_load_lds(
        (const __attribute__((address_space(1))) unsigned int*)g,
        (__attribute__((address_space(3))) unsigned int*)s, 16, 0, 0);
}

// ---------------------------------------------------------------------------
// Pack u -> A' bf16 [L][2H]: cols [0,1024)=u_r, [1024,2048)=u_i
// ---------------------------------------------------------------------------
__global__ void pack_u(const float* __restrict__ R, const float* __restrict__ I,
                       u16* __restrict__ A) {
    size_t t = (size_t)blockIdx.x * 256 + threadIdx.x;
    size_t base = t * 4;                      // over L*H
    int lrow = (int)(base >> 10);
    int h    = (int)(base & 1023);
    float4 r  = *reinterpret_cast<const float4*>(R + base);
    float4 im = *reinterpret_cast<const float4*>(I + base);
    u16* p0 = A + ((size_t)lrow << 11) + h;
    *reinterpret_cast<ushort4*>(p0) =
        make_ushort4(f2bf(r.x), f2bf(r.y), f2bf(r.z), f2bf(r.w));
    *reinterpret_cast<ushort4*>(p0 + 1024) =
        make_ushort4(f2bf(im.x), f2bf(im.y), f2bf(im.z), f2bf(im.w));
}

// ---------------------------------------------------------------------------
// B_norm pack -> Bp bf16 [2N][2H]
// ---------------------------------------------------------------------------
__global__ void bnorm_pack(const float* __restrict__ Br, const float* __restrict__ Bi,
                           const float* __restrict__ G, u16* __restrict__ Bp) {
    size_t t = (size_t)blockIdx.x * 256 + threadIdx.x;
    size_t base = t * 4;                      // over N*H
    int n = (int)(base >> 10);
    int h = (int)(base & 1023);
    float g = G[n];
    float sg, cg;
    sincosf(g, &sg, &cg);
    float4 br = *reinterpret_cast<const float4*>(Br + base);
    float4 bi = *reinterpret_cast<const float4*>(Bi + base);
    float nr0 = br.x * cg - bi.x * sg, ni0 = br.x * sg + bi.x * cg;
    float nr1 = br.y * cg - bi.y * sg, ni1 = br.y * sg + bi.y * cg;
    float nr2 = br.z * cg - bi.z * sg, ni2 = br.z * sg + bi.z * cg;
    float nr3 = br.w * cg - bi.w * sg, ni3 = br.w * sg + bi.w * cg;
    u16* row0 = Bp + (size_t)n * K2;
    u16* row1 = Bp + (size_t)(N_DIM + n) * K2;
    *reinterpret_cast<ushort4*>(row0 + h) =
        make_ushort4(f2bf(nr0), f2bf(nr1), f2bf(nr2), f2bf(nr3));
    *reinterpret_cast<ushort4*>(row0 + 1024 + h) =
        make_ushort4(f2bf(-ni0), f2bf(-ni1), f2bf(-ni2), f2bf(-ni3));
    *reinterpret_cast<ushort4*>(row1 + h) =
        make_ushort4(f2bf(ni0), f2bf(ni1), f2bf(ni2), f2bf(ni3));
    *reinterpret_cast<ushort4*>(row1 + 1024 + h) =
        make_ushort4(f2bf(nr0), f2bf(nr1), f2bf(nr2), f2bf(nr3));
}

// ---------------------------------------------------------------------------
// C pack -> Cp bf16 [H][2N]: row h = [ C_r[h][:] | -C_i[h][:] ]
// ---------------------------------------------------------------------------
__global__ void pack_C(const float* __restrict__ Cr, const float* __restrict__ Ci,
                       u16* __restrict__ Cp) {
    size_t t = (size_t)blockIdx.x * 256 + threadIdx.x;
    size_t base = t * 4;                      // over H*N
    int h = (int)(base >> 10);
    int n = (int)(base & 1023);
    float4 cr = *reinterpret_cast<const float4*>(Cr + base);
    float4 ci = *reinterpret_cast<const float4*>(Ci + base);
    u16* row = Cp + (size_t)h * K2;
    *reinterpret_cast<ushort4*>(row + n) =
        make_ushort4(f2bf(cr.x), f2bf(cr.y), f2bf(cr.z), f2bf(cr.w));
    *reinterpret_cast<ushort4*>(row + 1024 + n) =
        make_ushort4(f2bf(-ci.x), f2bf(-ci.y), f2bf(-ci.z), f2bf(-ci.w));
}

// ---------------------------------------------------------------------------
// GEMM1: 256x256 tile, BK=64, 8 waves (2Mx4N), dbuf K-tile slots.
// Interleaved schedule, 2 barriers/tile, race-free by construction:
//   (tile t entered with tile t fully resident -- B2 of tile t-1)
//   READ kk0 (12 ds_read_b128) | STAGE A1(t+1) -> other slot | LGKM0 |
//   MFMA kk0 qn01 | READ kk1 | STAGE B1(t+1) | MFMA kk0 qn23 | LGKM0 |
//   B1 barrier (all waves' reads of slot s drained)
//   STAGE A0(t+2) -> slot s | MFMA kk1 qn01 | STAGE B0(t+2) | MFMA kk1 qn23 |
//   vmcnt(4) (t<nt-2; else 0) | B2 barrier (tile t+1 resident for all waves)
// vmcnt(4): stage queue is A1(t+1),B1(t+1),A0(t+2),B0(t+2); draining to 4
// loads completes everything older than the 2 newest halves = tile t+1.
// Stages into the other slot overwrite data whose readers drained before
// the PREVIOUS tile's B1 (>= 1 full barrier earlier).
// 3-bit slot swizzle (slot ^ (row&7)), both-sides. Out = A*B^T, bf16 store.
// ---------------------------------------------------------------------------
__global__ __launch_bounds__(512, 2) void gemm_pipe(
    const u16* __restrict__ A, const u16* __restrict__ B, int Klen, int lda,
    u16* __restrict__ OutB, int ldo) {
    constexpr int ABYTES = 256 * 128;          // 32KB
    constexpr int SLOT   = 2 * ABYTES;         // 64KB
    __shared__ __attribute__((aligned(128))) char lds[2 * SLOT];
    const int tid = threadIdx.x;
    const int l   = tid & 63;
    const int w   = tid >> 6;
    const int wm  = w >> 2;            // 0..1
    const int wn  = w & 3;             // 0..3
    const long bm = (long)blockIdx.x * 256;
    const long bn = (long)blockIdx.y * 256;

    f32x4 acc[8][4];
#pragma unroll
    for (int i = 0; i < 8; ++i)
#pragma unroll
        for (int j = 0; j < 4; ++j) acc[i][j] = (f32x4){0.f, 0.f, 0.f, 0.f};

    // staging: one gload = 512 thr x 16B = 8KB = 64 rows of 128B.
    // Half h = rows [h*128, h*128+128) -> 2 gloads per half.
    const int    lr        = tid >> 3;
    const int    swzcol    = (((tid & 7) ^ (lr & 7)) << 4);
    const size_t rowstride = (size_t)lda * 2;
    const size_t a_src0    = (size_t)(bm + lr) * rowstride + swzcol;
    const size_t b_src0    = (size_t)(bn + lr) * rowstride + swzcol;
    const char*  Agb       = (const char*)A;
    const char*  Bgb       = (const char*)B;
    const int nt = Klen / 64;

    auto STAGE_A = [&](int kt, int h) {
        if (kt >= nt) return;
        const size_t kofs = (size_t)kt * 128;
        char* d = lds + (kt & 1) * SLOT + h * 16384 + tid * 16;
#pragma unroll
        for (int j = 0; j < 2; ++j)
            gload_lds16(Agb + a_src0 + (size_t)(h * 128 + j * 64) * rowstride + kofs,
                        d + j * 8192);
    };
    auto STAGE_B = [&](int kt, int h) {
        if (kt >= nt) return;
        const size_t kofs = (size_t)kt * 128;
        char* d = lds + (kt & 1) * SLOT + ABYTES + h * 16384 + tid * 16;
#pragma unroll
        for (int j = 0; j < 2; ++j)
            gload_lds16(Bgb + b_src0 + (size_t)(h * 128 + j * 64) * rowstride + kofs,
                        d + j * 8192);
    };

    const int l15   = l & 15;
    const int lslot = l >> 4;

    auto READ_A = [&](bf16x8 (&af)[8], const char* lA, int kk) {
#pragma unroll
        for (int mi = 0; mi < 8; ++mi) {
            int r   = wm * 128 + mi * 16 + l15;
            int sl3 = ((kk << 2) | lslot) ^ (r & 7);
            af[mi]  = *reinterpret_cast<const bf16x8*>(lA + r * 128 + sl3 * 16);
        }
    };
    auto READ_B = [&](bf16x8 (&bg)[4], const char* lB, int kk) {
#pragma unroll
        for (int ni = 0; ni < 4; ++ni) {
            int r   = wn * 64 + ni * 16 + l15;
            int sl3 = ((kk << 2) | lslot) ^ (r & 7);
            bg[ni]  = *reinterpret_cast<const bf16x8*>(lB + r * 128 + sl3 * 16);
        }
    };
    auto MFMA_Q = [&](bf16x8 (&af)[8], bf16x8 (&bg)[4], int qn) {
        __builtin_amdgcn_s_setprio(1);
#pragma unroll
        for (int mi = 0; mi < 8; ++mi)
#pragma unroll
            for (int nj = 0; nj < 2; ++nj)
                acc[mi][qn * 2 + nj] = __builtin_amdgcn_mfma_f32_16x16x32_bf16(
                    af[mi], bg[qn * 2 + nj], acc[mi][qn * 2 + nj], 0, 0, 0);
        __builtin_amdgcn_s_setprio(0);
    };

#define SBAR  do { __builtin_amdgcn_sched_barrier(0);                        \
    __builtin_amdgcn_s_barrier();                                            \
    __builtin_amdgcn_sched_barrier(0); } while (0)
#define LGKM0 do { asm volatile("s_waitcnt lgkmcnt(0)" ::: "memory");        \
    __builtin_amdgcn_sched_barrier(0); } while (0)

    // Prologue: tile0 all 4 halves + tile1 {A0,B0}; vmcnt(4) leaves only
    // tile1's 2 halves in flight -> tile0 resident; barrier publishes.
    STAGE_A(0, 0); STAGE_B(0, 0); STAGE_A(0, 1); STAGE_B(0, 1);
    STAGE_A(1, 0); STAGE_B(1, 0);
    asm volatile("s_waitcnt vmcnt(4)" ::: "memory");
    SBAR;

    bf16x8 af0[8], af1[8], bg0[4], bg1[4];

    for (int t = 0; t < nt; ++t) {
        const char* lA = lds + (t & 1) * SLOT;
        const char* lB = lA + ABYTES;
        // ---- first half: kk0 reads+MFMA, kk1 reads issued ----------------
        READ_A(af0, lA, 0);
        READ_B(bg0, lB, 0);
        STAGE_A(t + 1, 1);                 // other slot; readers drained at
                                           // tile t-1's B1
        LGKM0;                             // af0/bg0 ready
        MFMA_Q(af0, bg0, 0);
        READ_A(af1, lA, 1);
        READ_B(bg1, lB, 1);
        STAGE_B(t + 1, 1);
        MFMA_Q(af0, bg0, 1);
        LGKM0;                             // af1/bg1 ready (all slot-s reads
                                           // by this wave drained)
        SBAR;                              // B1: ALL waves' slot-s reads done
        // ---- second half: kk1 MFMA, stage into freed slot s --------------
        STAGE_A(t + 2, 0);
        MFMA_Q(af1, bg1, 0);
        STAGE_B(t + 2, 0);
        MFMA_Q(af1, bg1, 1);
        if (t < nt - 2) asm volatile("s_waitcnt vmcnt(4)" ::: "memory");
        else            asm volatile("s_waitcnt vmcnt(0)" ::: "memory");
        SBAR;                              // B2: tile t+1 resident, all waves
    }
#undef SBAR
#undef LGKM0

    // C/D layout: col = lane&15, row = (lane>>4)*4 + reg
#pragma unroll
    for (int mi = 0; mi < 8; ++mi) {
        const long row0 = bm + wm * 128 + mi * 16 + ((l >> 4) << 2);
#pragma unroll
        for (int ni = 0; ni < 4; ++ni) {
            const long col = bn + wn * 64 + ni * 16 + l15;
#pragma unroll
            for (int r = 0; r < 4; ++r)
                OutB[(size_t)(row0 + r) * ldo + col] = f2bf(acc[mi][ni][r]);
        }
    }
}

// ---------------------------------------------------------------------------
// GEMM2 (round-8 proven): 128x128 tile, BK=64, 256 thr (4 waves 2Mx2N),
// 64KB LDS -> 2 blocks/CU. dbuf + counted vmcnt + 3-bit slot swizzle.
// Fused epilogue: OutF = acc + Dv[col] * Ur[row,col].
// ---------------------------------------------------------------------------
__global__ __launch_bounds__(256, 2) void gemm_small(
    const u16* __restrict__ A, const u16* __restrict__ B, int Klen, int lda,
    float* __restrict__ OutF, int ldo,
    const float* __restrict__ Dv, const float* __restrict__ Ur) {
    constexpr int ABYTES = 128 * 128;          // 16KB
    constexpr int SLOT   = 2 * ABYTES;         // 32KB (A+B)
    __shared__ __attribute__((aligned(128))) char lds[2 * SLOT];  // 64KB
    const int tid = threadIdx.x;
    const int l   = tid & 63;
    const int w   = tid >> 6;          // 0..3
    const int wm  = w >> 1;            // 0..1
    const int wn  = w & 1;             // 0..1
    const long bm = (long)blockIdx.x * 128;
    const long bn = (long)blockIdx.y * 128;

    f32x4 acc[4][4];
#pragma unroll
    for (int i = 0; i < 4; ++i)
#pragma unroll
        for (int j = 0; j < 4; ++j) acc[i][j] = (f32x4){0.f, 0.f, 0.f, 0.f};

    const int    lr        = tid >> 3;                    // 0..31
    const int    swzcol    = (((tid & 7) ^ (lr & 7)) << 4);
    const size_t rowstride = (size_t)lda * 2;
    const size_t a_src0    = (size_t)(bm + lr) * rowstride + swzcol;
    const size_t b_src0    = (size_t)(bn + lr) * rowstride + swzcol;
    const char*  Agb       = (const char*)A;
    const char*  Bgb       = (const char*)B;

    auto STAGE = [&](int kt, int sl) {
        const size_t kofs = (size_t)kt * 128;
        char* la = lds + sl * SLOT + tid * 16;
        char* lb = lds + sl * SLOT + ABYTES + tid * 16;
#pragma unroll
        for (int j = 0; j < 4; ++j)
            gload_lds16(Agb + a_src0 + (size_t)j * 32 * rowstride + kofs,
                        la + j * 4096);
#pragma unroll
        for (int j = 0; j < 4; ++j)
            gload_lds16(Bgb + b_src0 + (size_t)j * 32 * rowstride + kofs,
                        lb + j * 4096);
    };

    const int l15   = l & 15;
    const int lslot = l >> 4;

    const int nt = Klen / 64;
    STAGE(0, 0);
    STAGE(1, 1);

    for (int t = 0; t < nt; ++t) {
        const int s = t & 1;
        if (t < nt - 1) asm volatile("s_waitcnt vmcnt(8)" ::: "memory");
        else            asm volatile("s_waitcnt vmcnt(0)" ::: "memory");
        __builtin_amdgcn_sched_barrier(0);
        __builtin_amdgcn_s_barrier();
        __builtin_amdgcn_sched_barrier(0);

        const char* lA = lds + s * SLOT;
        const char* lB = lA + ABYTES;
#pragma unroll
        for (int kk = 0; kk < 2; ++kk) {
            bf16x8 af[4], bg[4];
#pragma unroll
            for (int mi = 0; mi < 4; ++mi) {
                int r   = wm * 64 + mi * 16 + l15;
                int sl3 = ((kk << 2) | lslot) ^ (r & 7);
                af[mi]  = *reinterpret_cast<const bf16x8*>(lA + r * 128 + sl3 * 16);
            }
#pragma unroll
            for (int ni = 0; ni < 4; ++ni) {
                int r   = wn * 64 + ni * 16 + l15;
                int sl3 = ((kk << 2) | lslot) ^ (r & 7);
                bg[ni]  = *reinterpret_cast<const bf16x8*>(lB + r * 128 + sl3 * 16);
            }
            __builtin_amdgcn_s_setprio(1);
#pragma unroll
            for (int mi = 0; mi < 4; ++mi)
#pragma unroll
                for (int ni = 0; ni < 4; ++ni)
                    acc[mi][ni] = __builtin_amdgcn_mfma_f32_16x16x32_bf16(
                        af[mi], bg[ni], acc[mi][ni], 0, 0, 0);
            __builtin_amdgcn_s_setprio(0);
        }
        __builtin_amdgcn_sched_barrier(0);
        __builtin_amdgcn_s_barrier();
        __builtin_amdgcn_sched_barrier(0);
        if (t + 2 < nt) STAGE(t + 2, s);
    }

    // epilogue with fused D*u_r
#pragma unroll
    for (int mi = 0; mi < 4; ++mi) {
        const long row0 = bm + wm * 64 + mi * 16 + ((l >> 4) << 2);
#pragma unroll
        for (int ni = 0; ni < 4; ++ni) {
            const long col = bn + wn * 64 + ni * 16 + l15;
            const float d = Dv[col];
#pragma unroll
            for (int r = 0; r < 4; ++r) {
                size_t o = (size_t)(row0 + r) * ldo + col;
                OutF[o] = acc[mi][ni][r] + d * Ur[o];
            }
        }
    }
}

// ---------------------------------------------------------------------------
// Scan pass A (read-only): per-(chunk, channel-pair) summaries, 4B loads.
// NCHUNK=256 -> 512 blocks (2/CU), 32-step chains (latency-friendly).
// ---------------------------------------------------------------------------
__global__ void scan_sum(const u16* __restrict__ X,
                         const float* __restrict__ nu_log,
                         const float* __restrict__ theta_log,
                         float* __restrict__ Acr, float* __restrict__ Aci,
                         float* __restrict__ bcr, float* __restrict__ bci) {
    int n0 = (blockIdx.y * 256 + threadIdx.x) * 2;   // channel pair
    int c  = blockIdx.x;
    float lr0, li0, lr1, li1;
    {
        float m0 = expf(-expf(nu_log[n0]));
        float t0 = expf(theta_log[n0]);
        float s0, c0; sincosf(t0, &s0, &c0);
        lr0 = m0 * c0; li0 = m0 * s0;
        float m1 = expf(-expf(nu_log[n0 + 1]));
        float t1 = expf(theta_log[n0 + 1]);
        float s1, c1; sincosf(t1, &s1, &c1);
        lr1 = m1 * c1; li1 = m1 * s1;
    }
    float sr0 = 0.f, si0 = 0.f, pr0 = 1.f, pi0 = 0.f;
    float sr1 = 0.f, si1 = 0.f, pr1 = 1.f, pi1 = 0.f;
    size_t base = (size_t)c * CHUNK * K2 + n0;
    for (int j = 0; j < CHUNK; ++j) {
        size_t idx = base + (size_t)j * K2;
        unsigned int ru = *reinterpret_cast<const unsigned int*>(X + idx);
        unsigned int iu = *reinterpret_cast<const unsigned int*>(X + idx + 1024);
        float br0 = bf2f((u16)ru), br1 = bf2f((u16)(ru >> 16));
        float bi0 = bf2f((u16)iu), bi1 = bf2f((u16)(iu >> 16));
        float nr0 = lr0 * sr0 - li0 * si0 + br0;
        float ni0 = lr0 * si0 + li0 * sr0 + bi0;
        sr0 = nr0; si0 = ni0;
        float nr1 = lr1 * sr1 - li1 * si1 + br1;
        float ni1 = lr1 * si1 + li1 * sr1 + bi1;
        sr1 = nr1; si1 = ni1;
        float q0 = lr0 * pr0 - li0 * pi0, q1 = lr0 * pi0 + li0 * pr0;
        pr0 = q0; pi0 = q1;
        float q2 = lr1 * pr1 - li1 * pi1, q3 = lr1 * pi1 + li1 * pr1;
        pr1 = q2; pi1 = q3;
    }
    Acr[c * N_DIM + n0] = pr0; Aci[c * N_DIM + n0] = pi0;
    bcr[c * N_DIM + n0] = sr0; bci[c * N_DIM + n0] = si0;
    Acr[c * N_DIM + n0 + 1] = pr1; Aci[c * N_DIM + n0 + 1] = pi1;
    bcr[c * N_DIM + n0 + 1] = sr1; bci[c * N_DIM + n0 + 1] = si1;
}

// ---------------------------------------------------------------------------
// Scan pass B: sequential scan over NCHUNK chunk summaries (fp32).
// ---------------------------------------------------------------------------
__global__ void scan_carry(const float* __restrict__ Acr, const float* __restrict__ Aci,
                           const float* __restrict__ bcr, const float* __restrict__ bci,
                           float* __restrict__ car, float* __restrict__ cai) {
    int n = blockIdx.x * 256 + threadIdx.x;
    float sr = 0.f, si = 0.f;
    for (int c = 0; c < NCHUNK; ++c) {
        car[c * N_DIM + n] = sr; cai[c * N_DIM + n] = si;
        float ar = Acr[c * N_DIM + n], ai = Aci[c * N_DIM + n];
        float nr = ar * sr - ai * si + bcr[c * N_DIM + n];
        float ni = ar * si + ai * sr + bci[c * N_DIM + n];
        sr = nr; si = ni;
    }
}

// ---------------------------------------------------------------------------
// Scan pass C: re-scan each chunk seeded with carry-in; write final x (bf16).
// ---------------------------------------------------------------------------
__global__ void scan_apply(u16* __restrict__ X,
                           const float* __restrict__ nu_log,
                           const float* __restrict__ theta_log,
                           const float* __restrict__ car, const float* __restrict__ cai) {
    int n0 = (blockIdx.y * 256 + threadIdx.x) * 2;
    int c  = blockIdx.x;
    float lr0, li0, lr1, li1;
    {
        float m0 = expf(-expf(nu_log[n0]));
        float t0 = expf(theta_log[n0]);
        float s0, c0; sincosf(t0, &s0, &c0);
        lr0 = m0 * c0; li0 = m0 * s0;
        float m1 = expf(-expf(nu_log[n0 + 1]));
        float t1 = expf(theta_log[n0 + 1]);
        float s1, c1; sincosf(t1, &s1, &c1);
        lr1 = m1 * c1; li1 = m1 * s1;
    }
    float sr0 = car[c * N_DIM + n0],     si0 = cai[c * N_DIM + n0];
    float sr1 = car[c * N_DIM + n0 + 1], si1 = cai[c * N_DIM + n0 + 1];
    size_t base = (size_t)c * CHUNK * K2 + n0;
    for (int j = 0; j < CHUNK; ++j) {
        size_t idx = base + (size_t)j * K2;
        unsigned int ru = *reinterpret_cast<const unsigned int*>(X + idx);
        unsigned int iu = *reinterpret_cast<const unsigned int*>(X + idx + 1024);
        float br0 = bf2f((u16)ru), br1 = bf2f((u16)(ru >> 16));
        float bi0 = bf2f((u16)iu), bi1 = bf2f((u16)(iu >> 16));
        float nr0 = lr0 * sr0 - li0 * si0 + br0;
        float ni0 = lr0 * si0 + li0 * sr0 + bi0;
        sr0 = nr0; si0 = ni0;
        float nr1 = lr1 * sr1 - li1 * si1 + br1;
        float ni1 = lr1 * si1 + li1 * sr1 + bi1;
        sr1 = nr1; si1 = ni1;
        *reinterpret_cast<unsigned int*>(X + idx) =
            (unsigned int)f2bf(sr0) | ((unsigned int)f2bf(sr1) << 16);
        *reinterpret_cast<unsigned int*>(X + idx + 1024) =
            (unsigned int)f2bf(si0) | ((unsigned int)f2bf(si1) << 16);
    }
}

// ---------------------------------------------------------------------------
// Launch
// ---------------------------------------------------------------------------
extern "C" void kernel_launch(void* const* d_in, const int* in_sizes, int n_in,
                              void* d_out, int out_size, void* d_ws, size_t ws_size,
                              hipStream_t stream) {
    (void)in_sizes; (void)n_in; (void)out_size; (void)ws_size;
    const float* input_real = (const float*)d_in[0];
    const float* input_imag = (const float*)d_in[1];
    const float* nu_log     = (const float*)d_in[2];
    const float* theta_log  = (const float*)d_in[3];
    const float* B_real     = (const float*)d_in[4];
    const float* B_imag     = (const float*)d_in[5];
    const float* C_real     = (const float*)d_in[6];
    const float* C_imag     = (const float*)d_in[7];
    const float* D          = (const float*)d_in[8];
    const float* gamma_log  = (const float*)d_in[9];
    float* y = (float*)d_out;

    // Workspace layout (bytes):
    // [2M, 34M)  A' bf16 [8192][2048]  (dead after gemm1)
    //   [2M, 6M)   Cp aliases A' head  (alive after pack_C)
    // [34M, 42M) Bp bf16 [2048][2048]  (dead after gemm1)
    //   [34M, 40M) Acr..cai (6 x 1MB) alias Bp (alive after gemm1)
    // [42M, 74M) X  bf16 [8192][2048]  (Bu -> x in place)
    char* ws = (char*)d_ws;
    u16* Ap   = (u16*)(ws + ((size_t)2 << 20));
    u16* Cp   = Ap;                                 // alias: used after gemm1
    u16* Bp   = (u16*)(ws + ((size_t)34 << 20));
    float* Acr = (float*)(ws + ((size_t)34 << 20)); // alias Bp: used after gemm1
    float* Aci = Acr + NCHUNK * N_DIM;
    float* bcr = Aci + NCHUNK * N_DIM;
    float* bci = bcr + NCHUNK * N_DIM;
    float* car = bci + NCHUNK * N_DIM;
    float* cai = car + NCHUNK * N_DIM;
    u16* X    = (u16*)(ws + ((size_t)42 << 20));

    pack_u<<<(L_SEQ * H_DIM / 4) / 256, 256, 0, stream>>>(input_real, input_imag, Ap);
    bnorm_pack<<<(N_DIM * H_DIM / 4) / 256, 256, 0, stream>>>(B_real, B_imag, gamma_log, Bp);
    // GEMM1: 256x256 tile, grid 32x8 = 256 blocks (1/CU), K=2048
    gemm_pipe<<<dim3(L_SEQ / 256, K2 / 256), 512, 0, stream>>>(
        Ap, Bp, K2, K2, X, K2);
    scan_sum<<<dim3(NCHUNK, N_DIM / 512), 256, 0, stream>>>(
        X, nu_log, theta_log, Acr, Aci, bcr, bci);
    scan_carry<<<N_DIM / 256, 256, 0, stream>>>(Acr, Aci, bcr, bci, car, cai);
    scan_apply<<<dim3(NCHUNK, N_DIM / 512), 256, 0, stream>>>(
        X, nu_log, theta_log, car, cai);
    pack_C<<<(H_DIM * N_DIM / 4) / 256, 256, 0, stream>>>(C_real, C_imag, Cp);
    // GEMM2: 128x128 tile, grid 64x8 = 512 blocks (2/CU), K=2048, fused D*u
    gemm_small<<<dim3(L_SEQ / 128, H_DIM / 128), 256, 0, stream>>>(
        X, Cp, K2, K2, y, H_DIM, D, input_real);
}

// Round 11
// 153.701 us; speedup vs baseline: 1.2200x; 1.1107x over previous
//
#include <hip/hip_runtime.h>
#include <math.h>

#define L_SEQ 8192
#define H_DIM 1024
#define N_DIM 1024
#define K2    2048          // packed K = 2*H = 2*N
#define NCHUNK 256
#define CHUNK 32

typedef unsigned short u16;
typedef __attribute__((ext_vector_type(8))) __bf16 bf16x8;
typedef __attribute__((ext_vector_type(4))) float  f32x4;

__device__ __forceinline__ u16 f2bf(float x) {
    unsigned int u = __float_as_uint(x);
    u = (u + 0x7fffu + ((u >> 16) & 1u)) >> 16;   // RNE
    return (u16)u;
}
__device__ __forceinline__ float bf2f(u16 h) {
    return __uint_as_float(((unsigned int)h) << 16);
}

__device__ __forceinline__ void gload_lds16(const void* g, void* s) {
    __builtin_amdgcn_global_load_lds(
        (const __attribute__((address_space(1))) unsigned int*)g,
        (__attribute__((address_space(3))) unsigned int*)s, 16, 0, 0);
}

// ---------------------------------------------------------------------------
// Pack u -> A' bf16 [L][2H]: cols [0,1024)=u_r, [1024,2048)=u_i
// ---------------------------------------------------------------------------
__global__ void pack_u(const float* __restrict__ R, const float* __restrict__ I,
                       u16* __restrict__ A) {
    size_t t = (size_t)blockIdx.x * 256 + threadIdx.x;
    size_t base = t * 4;                      // over L*H
    int lrow = (int)(base >> 10);
    int h    = (int)(base & 1023);
    float4 r  = *reinterpret_cast<const float4*>(R + base);
    float4 im = *reinterpret_cast<const float4*>(I + base);
    u16* p0 = A + ((size_t)lrow << 11) + h;
    *reinterpret_cast<ushort4*>(p0) =
        make_ushort4(f2bf(r.x), f2bf(r.y), f2bf(r.z), f2bf(r.w));
    *reinterpret_cast<ushort4*>(p0 + 1024) =
        make_ushort4(f2bf(im.x), f2bf(im.y), f2bf(im.z), f2bf(im.w));
}

// ---------------------------------------------------------------------------
// B_norm pack -> Bp bf16 [2N][2H]
// ---------------------------------------------------------------------------
__global__ void bnorm_pack(const float* __restrict__ Br, const float* __restrict__ Bi,
                           const float* __restrict__ G, u16* __restrict__ Bp) {
    size_t t = (size_t)blockIdx.x * 256 + threadIdx.x;
    size_t base = t * 4;                      // over N*H
    int n = (int)(base >> 10);
    int h = (int)(base & 1023);
    float g = G[n];
    float sg, cg;
    sincosf(g, &sg, &cg);
    float4 br = *reinterpret_cast<const float4*>(Br + base);
    float4 bi = *reinterpret_cast<const float4*>(Bi + base);
    float nr0 = br.x * cg - bi.x * sg, ni0 = br.x * sg + bi.x * cg;
    float nr1 = br.y * cg - bi.y * sg, ni1 = br.y * sg + bi.y * cg;
    float nr2 = br.z * cg - bi.z * sg, ni2 = br.z * sg + bi.z * cg;
    float nr3 = br.w * cg - bi.w * sg, ni3 = br.w * sg + bi.w * cg;
    u16* row0 = Bp + (size_t)n * K2;
    u16* row1 = Bp + (size_t)(N_DIM + n) * K2;
    *reinterpret_cast<ushort4*>(row0 + h) =
        make_ushort4(f2bf(nr0), f2bf(nr1), f2bf(nr2), f2bf(nr3));
    *reinterpret_cast<ushort4*>(row0 + 1024 + h) =
        make_ushort4(f2bf(-ni0), f2bf(-ni1), f2bf(-ni2), f2bf(-ni3));
    *reinterpret_cast<ushort4*>(row1 + h) =
        make_ushort4(f2bf(ni0), f2bf(ni1), f2bf(ni2), f2bf(ni3));
    *reinterpret_cast<ushort4*>(row1 + 1024 + h) =
        make_ushort4(f2bf(nr0), f2bf(nr1), f2bf(nr2), f2bf(nr3));
}

// ---------------------------------------------------------------------------
// C pack -> Cp bf16 [H][2N]: row h = [ C_r[h][:] | -C_i[h][:] ]
// ---------------------------------------------------------------------------
__global__ void pack_C(const float* __restrict__ Cr, const float* __restrict__ Ci,
                       u16* __restrict__ Cp) {
    size_t t = (size_t)blockIdx.x * 256 + threadIdx.x;
    size_t base = t * 4;                      // over H*N
    int h = (int)(base >> 10);
    int n = (int)(base & 1023);
    float4 cr = *reinterpret_cast<const float4*>(Cr + base);
    float4 ci = *reinterpret_cast<const float4*>(Ci + base);
    u16* row = Cp + (size_t)h * K2;
    *reinterpret_cast<ushort4*>(row + n) =
        make_ushort4(f2bf(cr.x), f2bf(cr.y), f2bf(cr.z), f2bf(cr.w));
    *reinterpret_cast<ushort4*>(row + 1024 + n) =
        make_ushort4(f2bf(-ci.x), f2bf(-ci.y), f2bf(-ci.z), f2bf(-ci.w));
}

// ---------------------------------------------------------------------------
// GEMM1 (round-10 proven): 256x256 tile, BK=64, 8 waves (2Mx4N), dbuf slots.
// Interleaved schedule, 2 barriers/tile, race-free (see r10 derivation).
// 3-bit slot swizzle (slot ^ (row&7)), both-sides. Out = A*B^T, bf16 store.
// ---------------------------------------------------------------------------
__global__ __launch_bounds__(512, 2) void gemm_pipe(
    const u16* __restrict__ A, const u16* __restrict__ B, int Klen, int lda,
    u16* __restrict__ OutB, int ldo) {
    constexpr int ABYTES = 256 * 128;          // 32KB
    constexpr int SLOT   = 2 * ABYTES;         // 64KB
    __shared__ __attribute__((aligned(128))) char lds[2 * SLOT];
    const int tid = threadIdx.x;
    const int l   = tid & 63;
    const int w   = tid >> 6;
    const int wm  = w >> 2;            // 0..1
    const int wn  = w & 3;             // 0..3
    const long bm = (long)blockIdx.x * 256;
    const long bn = (long)blockIdx.y * 256;

    f32x4 acc[8][4];
#pragma unroll
    for (int i = 0; i < 8; ++i)
#pragma unroll
        for (int j = 0; j < 4; ++j) acc[i][j] = (f32x4){0.f, 0.f, 0.f, 0.f};

    const int    lr        = tid >> 3;
    const int    swzcol    = (((tid & 7) ^ (lr & 7)) << 4);
    const size_t rowstride = (size_t)lda * 2;
    const size_t a_src0    = (size_t)(bm + lr) * rowstride + swzcol;
    const size_t b_src0    = (size_t)(bn + lr) * rowstride + swzcol;
    const char*  Agb       = (const char*)A;
    const char*  Bgb       = (const char*)B;
    const int nt = Klen / 64;

    auto STAGE_A = [&](int kt, int h) {
        if (kt >= nt) return;
        const size_t kofs = (size_t)kt * 128;
        char* d = lds + (kt & 1) * SLOT + h * 16384 + tid * 16;
#pragma unroll
        for (int j = 0; j < 2; ++j)
            gload_lds16(Agb + a_src0 + (size_t)(h * 128 + j * 64) * rowstride + kofs,
                        d + j * 8192);
    };
    auto STAGE_B = [&](int kt, int h) {
        if (kt >= nt) return;
        const size_t kofs = (size_t)kt * 128;
        char* d = lds + (kt & 1) * SLOT + ABYTES + h * 16384 + tid * 16;
#pragma unroll
        for (int j = 0; j < 2; ++j)
            gload_lds16(Bgb + b_src0 + (size_t)(h * 128 + j * 64) * rowstride + kofs,
                        d + j * 8192);
    };

    const int l15   = l & 15;
    const int lslot = l >> 4;

    auto READ_A = [&](bf16x8 (&af)[8], const char* lA, int kk) {
#pragma unroll
        for (int mi = 0; mi < 8; ++mi) {
            int r   = wm * 128 + mi * 16 + l15;
            int sl3 = ((kk << 2) | lslot) ^ (r & 7);
            af[mi]  = *reinterpret_cast<const bf16x8*>(lA + r * 128 + sl3 * 16);
        }
    };
    auto READ_B = [&](bf16x8 (&bg)[4], const char* lB, int kk) {
#pragma unroll
        for (int ni = 0; ni < 4; ++ni) {
            int r   = wn * 64 + ni * 16 + l15;
            int sl3 = ((kk << 2) | lslot) ^ (r & 7);
            bg[ni]  = *reinterpret_cast<const bf16x8*>(lB + r * 128 + sl3 * 16);
        }
    };
    auto MFMA_Q = [&](bf16x8 (&af)[8], bf16x8 (&bg)[4], int qn) {
        __builtin_amdgcn_s_setprio(1);
#pragma unroll
        for (int mi = 0; mi < 8; ++mi)
#pragma unroll
            for (int nj = 0; nj < 2; ++nj)
                acc[mi][qn * 2 + nj] = __builtin_amdgcn_mfma_f32_16x16x32_bf16(
                    af[mi], bg[qn * 2 + nj], acc[mi][qn * 2 + nj], 0, 0, 0);
        __builtin_amdgcn_s_setprio(0);
    };

#define SBAR  do { __builtin_amdgcn_sched_barrier(0);                        \
    __builtin_amdgcn_s_barrier();                                            \
    __builtin_amdgcn_sched_barrier(0); } while (0)
#define LGKM0 do { asm volatile("s_waitcnt lgkmcnt(0)" ::: "memory");        \
    __builtin_amdgcn_sched_barrier(0); } while (0)

    STAGE_A(0, 0); STAGE_B(0, 0); STAGE_A(0, 1); STAGE_B(0, 1);
    STAGE_A(1, 0); STAGE_B(1, 0);
    asm volatile("s_waitcnt vmcnt(4)" ::: "memory");
    SBAR;

    bf16x8 af0[8], af1[8], bg0[4], bg1[4];

    for (int t = 0; t < nt; ++t) {
        const char* lA = lds + (t & 1) * SLOT;
        const char* lB = lA + ABYTES;
        READ_A(af0, lA, 0);
        READ_B(bg0, lB, 0);
        STAGE_A(t + 1, 1);
        LGKM0;
        MFMA_Q(af0, bg0, 0);
        READ_A(af1, lA, 1);
        READ_B(bg1, lB, 1);
        STAGE_B(t + 1, 1);
        MFMA_Q(af0, bg0, 1);
        LGKM0;
        SBAR;                              // B1: all waves' slot-s reads done
        STAGE_A(t + 2, 0);
        MFMA_Q(af1, bg1, 0);
        STAGE_B(t + 2, 0);
        MFMA_Q(af1, bg1, 1);
        if (t < nt - 2) asm volatile("s_waitcnt vmcnt(4)" ::: "memory");
        else            asm volatile("s_waitcnt vmcnt(0)" ::: "memory");
        SBAR;                              // B2: tile t+1 resident, all waves
    }
#undef SBAR
#undef LGKM0

    // C/D layout: col = lane&15, row = (lane>>4)*4 + reg
#pragma unroll
    for (int mi = 0; mi < 8; ++mi) {
        const long row0 = bm + wm * 128 + mi * 16 + ((l >> 4) << 2);
#pragma unroll
        for (int ni = 0; ni < 4; ++ni) {
            const long col = bn + wn * 64 + ni * 16 + l15;
#pragma unroll
            for (int r = 0; r < 4; ++r)
                OutB[(size_t)(row0 + r) * ldo + col] = f2bf(acc[mi][ni][r]);
        }
    }
}

// ---------------------------------------------------------------------------
// GEMM2: 128x128 tile, 4 waves (2Mx2N), 64KB LDS -> 2 blocks/CU, with the
// SAME interleaved 2-barrier schedule as GEMM1 (halves = 64 rows, 2 gloads).
// Residency/overwrite invariants identical (vmcnt(4) at B2, tail vmcnt(0)).
// Fused epilogue: OutF = acc + Dv[col] * Ur[row,col].
// ---------------------------------------------------------------------------
__global__ __launch_bounds__(256, 2) void gemm_small(
    const u16* __restrict__ A, const u16* __restrict__ B, int Klen, int lda,
    float* __restrict__ OutF, int ldo,
    const float* __restrict__ Dv, const float* __restrict__ Ur) {
    constexpr int ABYTES = 128 * 128;          // 16KB
    constexpr int SLOT   = 2 * ABYTES;         // 32KB (A+B)
    __shared__ __attribute__((aligned(128))) char lds[2 * SLOT];  // 64KB
    const int tid = threadIdx.x;
    const int l   = tid & 63;
    const int w   = tid >> 6;          // 0..3
    const int wm  = w >> 1;            // 0..1
    const int wn  = w & 1;             // 0..1
    const long bm = (long)blockIdx.x * 128;
    const long bn = (long)blockIdx.y * 128;

    f32x4 acc[4][4];
#pragma unroll
    for (int i = 0; i < 4; ++i)
#pragma unroll
        for (int j = 0; j < 4; ++j) acc[i][j] = (f32x4){0.f, 0.f, 0.f, 0.f};

    const int    lr        = tid >> 3;                    // 0..31
    const int    swzcol    = (((tid & 7) ^ (lr & 7)) << 4);
    const size_t rowstride = (size_t)lda * 2;
    const size_t a_src0    = (size_t)(bm + lr) * rowstride + swzcol;
    const size_t b_src0    = (size_t)(bn + lr) * rowstride + swzcol;
    const char*  Agb       = (const char*)A;
    const char*  Bgb       = (const char*)B;
    const int nt = Klen / 64;

    auto STAGE_A = [&](int kt, int h) {
        if (kt >= nt) return;
        const size_t kofs = (size_t)kt * 128;
        char* d = lds + (kt & 1) * SLOT + h * 8192 + tid * 16;
#pragma unroll
        for (int j = 0; j < 2; ++j)
            gload_lds16(Agb + a_src0 + (size_t)(h * 64 + j * 32) * rowstride + kofs,
                        d + j * 4096);
    };
    auto STAGE_B = [&](int kt, int h) {
        if (kt >= nt) return;
        const size_t kofs = (size_t)kt * 128;
        char* d = lds + (kt & 1) * SLOT + ABYTES + h * 8192 + tid * 16;
#pragma unroll
        for (int j = 0; j < 2; ++j)
            gload_lds16(Bgb + b_src0 + (size_t)(h * 64 + j * 32) * rowstride + kofs,
                        d + j * 4096);
    };

    const int l15   = l & 15;
    const int lslot = l >> 4;

    auto READ_A = [&](bf16x8 (&af)[4], const char* lA, int kk) {
#pragma unroll
        for (int mi = 0; mi < 4; ++mi) {
            int r   = wm * 64 + mi * 16 + l15;
            int sl3 = ((kk << 2) | lslot) ^ (r & 7);
            af[mi]  = *reinterpret_cast<const bf16x8*>(lA + r * 128 + sl3 * 16);
        }
    };
    auto READ_B = [&](bf16x8 (&bg)[4], const char* lB, int kk) {
#pragma unroll
        for (int ni = 0; ni < 4; ++ni) {
            int r   = wn * 64 + ni * 16 + l15;
            int sl3 = ((kk << 2) | lslot) ^ (r & 7);
            bg[ni]  = *reinterpret_cast<const bf16x8*>(lB + r * 128 + sl3 * 16);
        }
    };
    auto MFMA_Q = [&](bf16x8 (&af)[4], bf16x8 (&bg)[4], int qn) {
        __builtin_amdgcn_s_setprio(1);
#pragma unroll
        for (int mi = 0; mi < 4; ++mi)
#pragma unroll
            for (int nj = 0; nj < 2; ++nj)
                acc[mi][qn * 2 + nj] = __builtin_amdgcn_mfma_f32_16x16x32_bf16(
                    af[mi], bg[qn * 2 + nj], acc[mi][qn * 2 + nj], 0, 0, 0);
        __builtin_amdgcn_s_setprio(0);
    };

#define SBAR  do { __builtin_amdgcn_sched_barrier(0);                        \
    __builtin_amdgcn_s_barrier();                                            \
    __builtin_amdgcn_sched_barrier(0); } while (0)
#define LGKM0 do { asm volatile("s_waitcnt lgkmcnt(0)" ::: "memory");        \
    __builtin_amdgcn_sched_barrier(0); } while (0)

    STAGE_A(0, 0); STAGE_B(0, 0); STAGE_A(0, 1); STAGE_B(0, 1);
    STAGE_A(1, 0); STAGE_B(1, 0);
    asm volatile("s_waitcnt vmcnt(4)" ::: "memory");
    SBAR;

    bf16x8 af0[4], af1[4], bg0[4], bg1[4];

    for (int t = 0; t < nt; ++t) {
        const char* lA = lds + (t & 1) * SLOT;
        const char* lB = lA + ABYTES;
        READ_A(af0, lA, 0);
        READ_B(bg0, lB, 0);
        STAGE_A(t + 1, 1);
        LGKM0;
        MFMA_Q(af0, bg0, 0);
        READ_A(af1, lA, 1);
        READ_B(bg1, lB, 1);
        STAGE_B(t + 1, 1);
        MFMA_Q(af0, bg0, 1);
        LGKM0;
        SBAR;                              // B1
        STAGE_A(t + 2, 0);
        MFMA_Q(af1, bg1, 0);
        STAGE_B(t + 2, 0);
        MFMA_Q(af1, bg1, 1);
        if (t < nt - 2) asm volatile("s_waitcnt vmcnt(4)" ::: "memory");
        else            asm volatile("s_waitcnt vmcnt(0)" ::: "memory");
        SBAR;                              // B2
    }
#undef SBAR
#undef LGKM0

    // epilogue with fused D*u_r
#pragma unroll
    for (int mi = 0; mi < 4; ++mi) {
        const long row0 = bm + wm * 64 + mi * 16 + ((l >> 4) << 2);
#pragma unroll
        for (int ni = 0; ni < 4; ++ni) {
            const long col = bn + wn * 64 + ni * 16 + l15;
            const float d = Dv[col];
#pragma unroll
            for (int r = 0; r < 4; ++r) {
                size_t o = (size_t)(row0 + r) * ldo + col;
                OutF[o] = acc[mi][ni][r] + d * Ur[o];
            }
        }
    }
}

// ---------------------------------------------------------------------------
// Scan pass A (read-only): per-(chunk, channel-pair) final states only.
// A_c = Lambda^CHUNK is chunk-independent -> no A storage needed.
// Output layout [channel][chunk] for the wave-scan kernel.
// ---------------------------------------------------------------------------
__global__ void scan_sum(const u16* __restrict__ X,
                         const float* __restrict__ nu_log,
                         const float* __restrict__ theta_log,
                         float* __restrict__ bcr, float* __restrict__ bci) {
    int n0 = (blockIdx.y * 256 + threadIdx.x) * 2;   // channel pair
    int c  = blockIdx.x;
    float lr0, li0, lr1, li1;
    {
        float m0 = expf(-expf(nu_log[n0]));
        float t0 = expf(theta_log[n0]);
        float s0, c0; sincosf(t0, &s0, &c0);
        lr0 = m0 * c0; li0 = m0 * s0;
        float m1 = expf(-expf(nu_log[n0 + 1]));
        float t1 = expf(theta_log[n0 + 1]);
        float s1, c1; sincosf(t1, &s1, &c1);
        lr1 = m1 * c1; li1 = m1 * s1;
    }
    float sr0 = 0.f, si0 = 0.f, sr1 = 0.f, si1 = 0.f;
    size_t base = (size_t)c * CHUNK * K2 + n0;
    for (int j = 0; j < CHUNK; ++j) {
        size_t idx = base + (size_t)j * K2;
        unsigned int ru = *reinterpret_cast<const unsigned int*>(X + idx);
        unsigned int iu = *reinterpret_cast<const unsigned int*>(X + idx + 1024);
        float br0 = bf2f((u16)ru), br1 = bf2f((u16)(ru >> 16));
        float bi0 = bf2f((u16)iu), bi1 = bf2f((u16)(iu >> 16));
        float nr0 = lr0 * sr0 - li0 * si0 + br0;
        float ni0 = lr0 * si0 + li0 * sr0 + bi0;
        sr0 = nr0; si0 = ni0;
        float nr1 = lr1 * sr1 - li1 * si1 + br1;
        float ni1 = lr1 * si1 + li1 * sr1 + bi1;
        sr1 = nr1; si1 = ni1;
    }
    bcr[(size_t)n0 * NCHUNK + c] = sr0; bci[(size_t)n0 * NCHUNK + c] = si0;
    bcr[(size_t)(n0 + 1) * NCHUNK + c] = sr1; bci[(size_t)(n0 + 1) * NCHUNK + c] = si1;
}

// ---------------------------------------------------------------------------
// Scan pass B: wave-parallel scan over NCHUNK=256 chunk summaries.
// One wave per channel (256 blocks x 4 waves). Lane l owns chunks
// [4l, 4l+4): float4 load, local compose, 6-step shfl_up Hillis-Steele
// scan of (A,b), exclusive shift, expand -> car/cai in [channel][chunk].
// A of every chunk = Lambda^CHUNK (computed in closed form).
// ---------------------------------------------------------------------------
__global__ void scan_carry(const float* __restrict__ bcr, const float* __restrict__ bci,
                           const float* __restrict__ nu_log,
                           const float* __restrict__ theta_log,
                           float* __restrict__ car, float* __restrict__ cai) {
    const int lane = threadIdx.x & 63;
    const int n    = blockIdx.x * 4 + (threadIdx.x >> 6);
    // L = Lambda^CHUNK
    float mag = expf(-(float)CHUNK * expf(nu_log[n]));
    float ang = (float)CHUNK * expf(theta_log[n]);
    float sL, cL; sincosf(ang, &sL, &cL);
    const float Lr = mag * cL, Li = mag * sL;
    const size_t base = (size_t)n * NCHUNK + lane * 4;
    float4 br4 = *reinterpret_cast<const float4*>(bcr + base);
    float4 bi4 = *reinterpret_cast<const float4*>(bci + base);
    // local aggregate over 4 chunks: b = ((b0*L + b1)*L + b2)*L + b3, A = L^4
    float br = br4.x, bi = bi4.x;
    { float tr = Lr * br - Li * bi + br4.y, ti = Lr * bi + Li * br + bi4.y; br = tr; bi = ti; }
    { float tr = Lr * br - Li * bi + br4.z, ti = Lr * bi + Li * br + bi4.z; br = tr; bi = ti; }
    { float tr = Lr * br - Li * bi + br4.w, ti = Lr * bi + Li * br + bi4.w; br = tr; bi = ti; }
    float L2r = Lr * Lr - Li * Li, L2i = 2.f * Lr * Li;
    float Ar = L2r * L2r - L2i * L2i, Ai = 2.f * L2r * L2i;   // L^4
    // inclusive scan across lanes: new = self o prev
#pragma unroll
    for (int d = 1; d < 64; d <<= 1) {
        float pAr = __shfl_up(Ar, d);
        float pAi = __shfl_up(Ai, d);
        float pbr = __shfl_up(br, d);
        float pbi = __shfl_up(bi, d);
        if (lane >= d) {
            float nbr = Ar * pbr - Ai * pbi + br;
            float nbi = Ar * pbi + Ai * pbr + bi;
            float nAr = Ar * pAr - Ai * pAi;
            float nAi = Ar * pAi + Ai * pAr;
            br = nbr; bi = nbi; Ar = nAr; Ai = nAi;
        }
    }
    // exclusive: state entering lane's first chunk (s0 = 0 -> b-part only)
    float sr = __shfl_up(br, 1);
    float si = __shfl_up(bi, 1);
    if (lane == 0) { sr = 0.f; si = 0.f; }
    // expand within lane's 4 chunks
    float4 or4, oi4;
    or4.x = sr; oi4.x = si;
    { float tr = Lr * sr - Li * si + br4.x, ti = Lr * si + Li * sr + bi4.x; sr = tr; si = ti; }
    or4.y = sr; oi4.y = si;
    { float tr = Lr * sr - Li * si + br4.y, ti = Lr * si + Li * sr + bi4.y; sr = tr; si = ti; }
    or4.z = sr; oi4.z = si;
    { float tr = Lr * sr - Li * si + br4.z, ti = Lr * si + Li * sr + bi4.z; sr = tr; si = ti; }
    or4.w = sr; oi4.w = si;
    *reinterpret_cast<float4*>(car + base) = or4;
    *reinterpret_cast<float4*>(cai + base) = oi4;
}

// ---------------------------------------------------------------------------
// Scan pass C: re-scan each chunk seeded with carry-in; write final x (bf16).
// car/cai layout: [channel][chunk].
// ---------------------------------------------------------------------------
__global__ void scan_apply(u16* __restrict__ X,
                           const float* __restrict__ nu_log,
                           const float* __restrict__ theta_log,
                           const float* __restrict__ car, const float* __restrict__ cai) {
    int n0 = (blockIdx.y * 256 + threadIdx.x) * 2;
    int c  = blockIdx.x;
    float lr0, li0, lr1, li1;
    {
        float m0 = expf(-expf(nu_log[n0]));
        float t0 = expf(theta_log[n0]);
        float s0, c0; sincosf(t0, &s0, &c0);
        lr0 = m0 * c0; li0 = m0 * s0;
        float m1 = expf(-expf(nu_log[n0 + 1]));
        float t1 = expf(theta_log[n0 + 1]);
        float s1, c1; sincosf(t1, &s1, &c1);
        lr1 = m1 * c1; li1 = m1 * s1;
    }
    float sr0 = car[(size_t)n0 * NCHUNK + c],       si0 = cai[(size_t)n0 * NCHUNK + c];
    float sr1 = car[(size_t)(n0 + 1) * NCHUNK + c], si1 = cai[(size_t)(n0 + 1) * NCHUNK + c];
    size_t base = (size_t)c * CHUNK * K2 + n0;
    for (int j = 0; j < CHUNK; ++j) {
        size_t idx = base + (size_t)j * K2;
        unsigned int ru = *reinterpret_cast<const unsigned int*>(X + idx);
        unsigned int iu = *reinterpret_cast<const unsigned int*>(X + idx + 1024);
        float br0 = bf2f((u16)ru), br1 = bf2f((u16)(ru >> 16));
        float bi0 = bf2f((u16)iu), bi1 = bf2f((u16)(iu >> 16));
        float nr0 = lr0 * sr0 - li0 * si0 + br0;
        float ni0 = lr0 * si0 + li0 * sr0 + bi0;
        sr0 = nr0; si0 = ni0;
        float nr1 = lr1 * sr1 - li1 * si1 + br1;
        float ni1 = lr1 * si1 + li1 * sr1 + bi1;
        sr1 = nr1; si1 = ni1;
        *reinterpret_cast<unsigned int*>(X + idx) =
            (unsigned int)f2bf(sr0) | ((unsigned int)f2bf(sr1) << 16);
        *reinterpret_cast<unsigned int*>(X + idx + 1024) =
            (unsigned int)f2bf(si0) | ((unsigned int)f2bf(si1) << 16);
    }
}

// ---------------------------------------------------------------------------
// Launch
// ---------------------------------------------------------------------------
extern "C" void kernel_launch(void* const* d_in, const int* in_sizes, int n_in,
                              void* d_out, int out_size, void* d_ws, size_t ws_size,
                              hipStream_t stream) {
    (void)in_sizes; (void)n_in; (void)out_size; (void)ws_size;
    const float* input_real = (const float*)d_in[0];
    const float* input_imag = (const float*)d_in[1];
    const float* nu_log     = (const float*)d_in[2];
    const float* theta_log  = (const float*)d_in[3];
    const float* B_real     = (const float*)d_in[4];
    const float* B_imag     = (const float*)d_in[5];
    const float* C_real     = (const float*)d_in[6];
    const float* C_imag     = (const float*)d_in[7];
    const float* D          = (const float*)d_in[8];
    const float* gamma_log  = (const float*)d_in[9];
    float* y = (float*)d_out;

    // Workspace layout (bytes):
    // [2M, 34M)  A' bf16 [8192][2048]  (dead after gemm1)
    //   [2M, 6M)   Cp aliases A' head  (alive after pack_C)
    // [34M, 42M) Bp bf16 [2048][2048]  (dead after gemm1)
    //   [34M, 38M) bcr/bci/car/cai (4 x 1MB) alias Bp (alive after gemm1)
    // [42M, 74M) X  bf16 [8192][2048]  (Bu -> x in place)
    char* ws = (char*)d_ws;
    u16* Ap   = (u16*)(ws + ((size_t)2 << 20));
    u16* Cp   = Ap;                                 // alias: used after gemm1
    u16* Bp   = (u16*)(ws + ((size_t)34 << 20));
    float* bcr = (float*)(ws + ((size_t)34 << 20)); // alias Bp: used after gemm1
    float* bci = bcr + NCHUNK * N_DIM;
    float* car = bci + NCHUNK * N_DIM;
    float* cai = car + NCHUNK * N_DIM;
    u16* X    = (u16*)(ws + ((size_t)42 << 20));

    pack_u<<<(L_SEQ * H_DIM / 4) / 256, 256, 0, stream>>>(input_real, input_imag, Ap);
    bnorm_pack<<<(N_DIM * H_DIM / 4) / 256, 256, 0, stream>>>(B_real, B_imag, gamma_log, Bp);
    // GEMM1: 256x256 tile, grid 32x8 = 256 blocks (1/CU), K=2048
    gemm_pipe<<<dim3(L_SEQ / 256, K2 / 256), 512, 0, stream>>>(
        Ap, Bp, K2, K2, X, K2);
    scan_sum<<<dim3(NCHUNK, N_DIM / 512), 256, 0, stream>>>(
        X, nu_log, theta_log, bcr, bci);
    scan_carry<<<N_DIM / 4, 256, 0, stream>>>(bcr, bci, nu_log, theta_log, car, cai);
    scan_apply<<<dim3(NCHUNK, N_DIM / 512), 256, 0, stream>>>(
        X, nu_log, theta_log, car, cai);
    pack_C<<<(H_DIM * N_DIM / 4) / 256, 256, 0, stream>>>(C_real, C_imag, Cp);
    // GEMM2: 128x128 tile, grid 64x8 = 512 blocks (2/CU), K=2048, fused D*u
    gemm_small<<<dim3(L_SEQ / 128, H_DIM / 128), 256, 0, stream>>>(
        X, Cp, K2, K2, y, H_DIM, D, input_real);
}